// Round 9
// baseline (826.236 us; speedup 1.0000x reference)
//
#include <hip/hip_runtime.h>
#include <hip/hip_bf16.h>

#define EMB 128
#define EDGE 32
#define STEPS 3

typedef short bf8s __attribute__((ext_vector_type(8)));
typedef float f32x4 __attribute__((ext_vector_type(4)));

__device__ __forceinline__ float lrelu(float v) { return v > 0.0f ? v : 0.01f * v; }
__device__ __forceinline__ unsigned short f2bf(float f) {
    unsigned u = __float_as_uint(f);
    u += 0x7fffu + ((u >> 16) & 1u);
    return (unsigned short)(u >> 16);
}
__device__ __forceinline__ float bf2f(unsigned short s) {
    return __uint_as_float(((unsigned)s) << 16);
}
// packed fp32x2 -> bf16x2 (v_cvt_pk_bf16_f32 on gfx950)
__device__ __forceinline__ unsigned pk2bf(float x, float y) {
    __hip_bfloat162 h = __float22bfloat162_rn(make_float2(x, y));
    return *(unsigned*)&h;
}

// ---------------- CSR build ----------------
__global__ void k_hist(const int* __restrict__ dst, int E, int* __restrict__ deg) {
    int e = blockIdx.x * 256 + threadIdx.x;
    if (e < E) atomicAdd(&deg[dst[e]], 1);
}

__global__ void k_scan1(const int* __restrict__ deg, int N, int* __restrict__ rowptr,
                        int* __restrict__ bsums) {
    __shared__ int s[256];
    int t = threadIdx.x;
    int i = blockIdx.x * 256 + t;
    int v = (i < N) ? deg[i] : 0;
    s[t] = v;
    __syncthreads();
#pragma unroll
    for (int off = 1; off < 256; off <<= 1) {
        int x = (t >= off) ? s[t - off] : 0;
        __syncthreads();
        s[t] += x;
        __syncthreads();
    }
    if (i < N) rowptr[i] = s[t] - v;
    if (t == 255) bsums[blockIdx.x] = s[255];
}

__global__ void k_scan2(int* __restrict__ bsums, int NB) {
    __shared__ int s[256];
    __shared__ int carry;
    int t = threadIdx.x;
    if (t == 0) carry = 0;
    __syncthreads();
    for (int base = 0; base < NB; base += 256) {
        int i = base + t;
        int v = (i < NB) ? bsums[i] : 0;
        s[t] = v;
        __syncthreads();
#pragma unroll
        for (int off = 1; off < 256; off <<= 1) {
            int x = (t >= off) ? s[t - off] : 0;
            __syncthreads();
            s[t] += x;
            __syncthreads();
        }
        int excl = s[t] - v + carry;
        if (i < NB) bsums[i] = excl;
        int tot = s[255];
        __syncthreads();
        if (t == 0) carry += tot;
        __syncthreads();
    }
}

// also materializes cursor (= rowptr copy) so no D2D memcpy is needed
__global__ void k_scan3(int* __restrict__ rowptr, const int* __restrict__ bsums,
                        int* __restrict__ cursor, int N, int E) {
    int i = blockIdx.x * 256 + threadIdx.x;
    if (i < N) {
        int v = rowptr[i] + bsums[i >> 8];
        rowptr[i] = v;
        cursor[i] = v;
    }
    if (i == 0) rowptr[N] = E;
}

// fill: CSR permutation -- scatter ONLY an 8B (src,e) record per edge.
__global__ void k_fill(const int* __restrict__ src, const int* __restrict__ dst, int E,
                       int* __restrict__ cursor, int2* __restrict__ sp2) {
    int e = blockIdx.x * 256 + threadIdx.x;
    if (e >= E) return;
    int d = dst[e];
    int p = atomicAdd(&cursor[d], 1);
    sp2[p] = make_int2(src[e], e);
}

// eaperm: p-contiguous pass. Reads sp2[p] (contiguous), gathers ea[e] as one
// FULL 128B line (no read amplification), writes bf16 row ea16p[p] and srcp[p]
// contiguously (perfectly coalesced).
__global__ __launch_bounds__(256) void k_eaperm(const float* __restrict__ ea,
                                                const int2* __restrict__ sp2,
                                                unsigned short* __restrict__ ea16p,
                                                int* __restrict__ srcp, int E) {
    int p = blockIdx.x * 256 + threadIdx.x;
    if (p >= E) return;
    int2 sp = sp2[p];
    srcp[p] = sp.x;
    const float4* er = (const float4*)(ea + (size_t)sp.y * EDGE);
    union { unsigned u[16]; int4 v[4]; } o;
#pragma unroll
    for (int q = 0; q < 8; ++q) {
        float4 v = er[q];
        o.u[2 * q]     = pk2bf(v.x, v.y);
        o.u[2 * q + 1] = pk2bf(v.z, v.w);
    }
    int4* dp = (int4*)(ea16p + (size_t)p * EDGE);
#pragma unroll
    for (int q = 0; q < 4; ++q) dp[q] = o.v[q];
}

// ---------------- fused one-time setup ----------------
// block ranges: [0,XB) x0->x16 bf16 cvt | [XB,XB+NB) zero deg |
// [XB+NB, XB+NB+G) gb0 + zero xg_a + gstart[g] | last block: hsent + gstart[G]
__global__ __launch_bounds__(256) void k_setup(const float* __restrict__ x0,
                                               unsigned short* __restrict__ x16,
                                               int N, int XB, int NB,
                                               const float* __restrict__ ba,
                                               float* __restrict__ gb,
                                               float* __restrict__ xg_a,
                                               const int* __restrict__ batch,
                                               int* __restrict__ gstart, int G,
                                               unsigned short* __restrict__ h16,
                                               int* __restrict__ deg) {
    int b = blockIdx.x, t = threadIdx.x;
    if (b < XB) {
        size_t idx = ((size_t)b * 256 + t) * 8;
        if (idx < (size_t)N * EMB) {
            const float4* s = (const float4*)(x0 + idx);
            float4 v0 = s[0], v1 = s[1];
            union { bf8s v; unsigned u[4]; } o;
            o.u[0] = pk2bf(v0.x, v0.y);
            o.u[1] = pk2bf(v0.z, v0.w);
            o.u[2] = pk2bf(v1.x, v1.y);
            o.u[3] = pk2bf(v1.z, v1.w);
            *(bf8s*)(x16 + idx) = o.v;
        }
        return;
    }
    b -= XB;
    if (b < NB) {
        int i = b * 256 + t;
        if (i < N) deg[i] = 0;
        return;
    }
    b -= NB;
    if (b < G) {
        if (t < EMB) gb[(size_t)b * EMB + t] = ba[t];
        else xg_a[(size_t)b * EMB + (t - EMB)] = 0.f;
        if (t == 0) {
            int lo = 0, hi = N;
            while (lo < hi) {
                int mid = (lo + hi) >> 1;
                if (batch[mid] < b) lo = mid + 1; else hi = mid;
            }
            gstart[b] = lo;
        }
        return;
    }
    // last block
    if (t < EMB) h16[(size_t)N * EMB + t] = 0xFF80u;   // -inf sentinel row
    if (t == EMB) gstart[G] = N;
}

// ---------------- weight prepack: fp32 row-major -> bf16 B-fragment order ----------------
__global__ __launch_bounds__(256) void k_wpack(const float* __restrict__ Wm,
                                               const float* __restrict__ Wa,
                                               const float* __restrict__ Wfeat,
                                               unsigned short* __restrict__ wpack) {
    int gid = blockIdx.x * 256 + threadIdx.x;
    int unit = gid >> 14;
    int e = gid & 16383;
    int s = unit / 5, u = unit % 5;
    const float* src; int rows;
    switch (u) {
        case 0: src = Wm + (size_t)s * 160 * EMB;             rows = 128; break;
        case 1: src = Wm + (size_t)s * 160 * EMB + 128 * EMB; rows = 32;  break;
        case 2: src = Wa + (size_t)s * 384 * EMB;             rows = 128; break;
        case 3: src = Wa + (size_t)s * 384 * EMB + 256 * EMB; rows = 128; break;
        default: src = Wfeat + (size_t)s * EMB * EMB;         rows = 128; break;
    }
    int k = e >> 7, n = e & 127;
    if (k >= rows) return;
    unsigned short b = f2bf(src[(size_t)k * EMB + n]);
    int kc = k >> 5, c = n >> 4, lane = (n & 15) | (((k & 31) >> 3) << 4), j = k & 7;
    wpack[(size_t)unit * 16384 + ((size_t)(kc * 8 + c) * 64 + lane) * 8 + j] = b;
}

// ---------------- MFMA GEMM core: 64-row x 128-col slab, K=128 ----------------
// NOTE: one packed weight unit = 128x128 bf16 = 16384 shorts = 32KB; lB buffers
// MUST be 16384 shorts (R8's 8192 was the correctness bug).
__device__ __forceinline__ void loadAa(const unsigned short* __restrict__ A16, int row0,
                                       int wv, int lane, int N, bf8s af[4]) {
    int li = lane & 15, oct = lane >> 4;
    int m = row0 + wv * 16 + li;
    if (m >= N) m = N - 1;
    const bf8s* ar = (const bf8s*)(A16 + (size_t)m * EMB);
#pragma unroll
    for (int kc = 0; kc < 4; ++kc) af[kc] = ar[kc * 4 + oct];
}
__device__ __forceinline__ void stageB(const unsigned short* __restrict__ Bp,
                                       unsigned short* lB, int tid) {
#pragma unroll
    for (int i = 0; i < 8; ++i) {
        int idx = tid + i * 256;
        ((int4*)lB)[idx] = ((const int4*)Bp)[idx];
    }
}
__device__ __forceinline__ void mfma128r(const bf8s af[4], const unsigned short* lB,
                                         f32x4 acc[8], int lane) {
#pragma unroll
    for (int kc = 0; kc < 4; ++kc) {
#pragma unroll
        for (int c = 0; c < 8; ++c) {
            bf8s b = *(const bf8s*)&lB[((kc * 8 + c) * 64 + lane) * 8];
            acc[c] = __builtin_amdgcn_mfma_f32_16x16x32_bf16(af[kc], b, acc[c], 0, 0, 0);
        }
    }
}

// h16 = bf16(x @ Wm_x + bm), COLUMN-SWIZZLED (col c at pos (c&15)*8 + (c>>4))
// so k_fagg's h-gather for lane li is ONE 16B load. 128 rows/block in two
// 64-row halves; weights staged once (halves block count + staging traffic).
__global__ __launch_bounds__(256) void k_gemm_bias(const unsigned short* __restrict__ A16,
                                                   const unsigned short* __restrict__ Bp,
                                                   const float* __restrict__ bias,
                                                   unsigned short* __restrict__ C, int N) {
    __shared__ unsigned short lB[16384];
    int tid = threadIdx.x, wv = tid >> 6, lane = tid & 63;
    stageB(Bp, lB, tid);
    __syncthreads();
    int li = lane & 15, quad = lane >> 4;
    float bcol[8];
#pragma unroll
    for (int c = 0; c < 8; ++c) bcol[c] = bias[c * 16 + li];
#pragma unroll
    for (int half = 0; half < 2; ++half) {
        int row0 = blockIdx.x * 128 + half * 64;
        if (row0 >= N) break;
        bf8s af[4];
        loadAa(A16, row0, wv, lane, N, af);
        f32x4 acc[8];
#pragma unroll
        for (int c = 0; c < 8; ++c) acc[c] = (f32x4){0.f, 0.f, 0.f, 0.f};
        mfma128r(af, lB, acc, lane);
#pragma unroll
        for (int rr = 0; rr < 4; ++rr) {
            int m = row0 + wv * 16 + quad * 4 + rr;
            if (m < N) {
                union { bf8s v; unsigned u[4]; } o;
#pragma unroll
                for (int j = 0; j < 4; ++j)
                    o.u[j] = pk2bf(acc[2 * j][rr] + bcol[2 * j],
                                   acc[2 * j + 1][rr] + bcol[2 * j + 1]);
                *(bf8s*)&C[(size_t)m * EMB + li * 8] = o.v;
            }
        }
    }
}

// epilogue for one 64-row half of k_gemm_node; each thread touches only its
// own (m,col) elements of x16 (read residual, write update) -- R7 semantics.
__device__ __forceinline__ void node_epi(const f32x4 acc[8], int row0, int wv, int lane,
                                         const float* __restrict__ gb,
                                         const int* __restrict__ batch,
                                         unsigned short* __restrict__ x16,
                                         float* __restrict__ xout_f32,
                                         const float* __restrict__ wg,
                                         const float* __restrict__ bg,
                                         float* __restrict__ gate, int N) {
    int li = lane & 15, quad = lane >> 4;
    float gpart[4] = {0.f, 0.f, 0.f, 0.f};
#pragma unroll
    for (int c = 0; c < 8; ++c) {
        int col = c * 16 + li;
        float wgc = wg[col];
#pragma unroll
        for (int rr = 0; rr < 4; ++rr) {
            int m = row0 + wv * 16 + quad * 4 + rr;
            if (m < N) {
                int g = batch[m];
                float b = gb[(size_t)g * EMB + col];
                float res = bf2f(x16[(size_t)m * EMB + col]);
                float v = lrelu(acc[c][rr] + b) + res;
                x16[(size_t)m * EMB + col] = f2bf(v);
                if (xout_f32) xout_f32[(size_t)m * EMB + col] = v;
                gpart[rr] = fmaf(v, wgc, gpart[rr]);
            }
        }
    }
#pragma unroll
    for (int rr = 0; rr < 4; ++rr) {
#pragma unroll
        for (int off = 1; off < 16; off <<= 1)
            gpart[rr] += __shfl_xor(gpart[rr], off, 64);
    }
    if (li == 0) {
        float b0 = bg[0];
#pragma unroll
        for (int rr = 0; rr < 4; ++rr) {
            int m = row0 + wv * 16 + quad * 4 + rr;
            if (m < N) gate[m] = gpart[rr] + b0;
        }
    }
}

// x_new = lrelu(x@Wa_x + agg16@Wa_agg + gb[batch]) + x ; fused gate = x_new.wg+bg
// bf16 node state (x16); fp32 materialized only on last step into d_out.
// 128 rows/block, TWO-PHASE staging in one 32KB buffer: stage Wa_x -> both
// halves' X-MFMA -> barrier -> stage Wa_agg -> both halves' agg-MFMA.
// Both halves' accumulators (64 VGPR) stay live across the restage.
__global__ __launch_bounds__(256) void k_gemm_node(unsigned short* __restrict__ x16,
                                                   const unsigned short* __restrict__ agg16,
                                                   const unsigned short* __restrict__ BpX,
                                                   const unsigned short* __restrict__ BpA,
                                                   const float* __restrict__ gb,
                                                   const int* __restrict__ batch,
                                                   float* __restrict__ xout_f32, // d_out or null
                                                   const float* __restrict__ wg,
                                                   const float* __restrict__ bg,
                                                   float* __restrict__ gate, int N) {
    __shared__ unsigned short lB[16384];
    int tid = threadIdx.x, wv = tid >> 6, lane = tid & 63;
    int row0 = blockIdx.x * 128;
    int row1 = row0 + 64;
    bool h1 = (row1 < N);
    stageB(BpX, lB, tid);
    __syncthreads();
    f32x4 acc0[8], acc1[8];
#pragma unroll
    for (int c = 0; c < 8; ++c) {
        acc0[c] = (f32x4){0.f, 0.f, 0.f, 0.f};
        acc1[c] = (f32x4){0.f, 0.f, 0.f, 0.f};
    }
    bf8s af[4];
    loadAa(x16, row0, wv, lane, N, af);
    mfma128r(af, lB, acc0, lane);
    if (h1) {
        loadAa(x16, row1, wv, lane, N, af);
        mfma128r(af, lB, acc1, lane);
    }
    __syncthreads();
    stageB(BpA, lB, tid);
    __syncthreads();
    loadAa(agg16, row0, wv, lane, N, af);
    mfma128r(af, lB, acc0, lane);
    if (h1) {
        loadAa(agg16, row1, wv, lane, N, af);
        mfma128r(af, lB, acc1, lane);
    }
    node_epi(acc0, row0, wv, lane, gb, batch, x16, xout_f32, wg, bg, gate, N);
    if (h1) node_epi(acc1, row1, wv, lane, gb, batch, x16, xout_f32, wg, bg, gate, N);
}

// pooled += alpha * lrelu(x@Wfeat + bfeat), accumulated directly (no ft16).
// 128 rows/block in two halves, weights staged once.
__global__ __launch_bounds__(256) void k_gemm_feat(const unsigned short* __restrict__ A16,
                                                   const unsigned short* __restrict__ Bp,
                                                   const float* __restrict__ bias,
                                                   const float* __restrict__ gate,
                                                   const float* __restrict__ gmax,
                                                   const float* __restrict__ denom,
                                                   const int* __restrict__ batch,
                                                   float* __restrict__ pooled, int N) {
    __shared__ unsigned short lB[16384];
    int tid = threadIdx.x, wv = tid >> 6, lane = tid & 63;
    stageB(Bp, lB, tid);
    __syncthreads();
    int li = lane & 15, quad = lane >> 4;
#pragma unroll
    for (int half = 0; half < 2; ++half) {
        int row0 = blockIdx.x * 128 + half * 64;
        if (row0 >= N) break;
        bf8s af[4];
        loadAa(A16, row0, wv, lane, N, af);
        f32x4 acc[8];
#pragma unroll
        for (int c = 0; c < 8; ++c) acc[c] = (f32x4){0.f, 0.f, 0.f, 0.f};
        mfma128r(af, lB, acc, lane);
        int rb = row0 + wv * 16;
        if (rb >= N) continue;
        float alpha[4];
        int grow[4];
#pragma unroll
        for (int rr = 0; rr < 4; ++rr) {
            int m = rb + quad * 4 + rr;
            if (m < N) {
                int g = batch[m];
                grow[rr] = g;
                alpha[rr] = __expf(gate[m] - gmax[g]) / denom[g];
            } else { alpha[rr] = 0.f; grow[rr] = 0; }
        }
        int gs = batch[rb];
        int mlast = rb + 15; if (mlast >= N) mlast = N - 1;
        bool uni = (gs == batch[mlast]);
#pragma unroll
        for (int c = 0; c < 8; ++c) {
            int col = c * 16 + li;
            float b = bias[col];
            float v0 = alpha[0] * lrelu(acc[c][0] + b);
            float v1 = alpha[1] * lrelu(acc[c][1] + b);
            float v2 = alpha[2] * lrelu(acc[c][2] + b);
            float v3 = alpha[3] * lrelu(acc[c][3] + b);
            if (uni) {
                float s = (v0 + v1) + (v2 + v3);
                s += __shfl_xor(s, 16, 64);
                s += __shfl_xor(s, 32, 64);
                if (quad == 0) atomicAdd(&pooled[(size_t)gs * EMB + col], s);
            } else {
                if (rb + quad * 4 + 0 < N) atomicAdd(&pooled[(size_t)grow[0] * EMB + col], v0);
                if (rb + quad * 4 + 1 < N) atomicAdd(&pooled[(size_t)grow[1] * EMB + col], v1);
                if (rb + quad * 4 + 2 < N) atomicAdd(&pooled[(size_t)grow[2] * EMB + col], v2);
                if (rb + quad * 4 + 3 < N) atomicAdd(&pooled[(size_t)grow[3] * EMB + col], v3);
            }
        }
    }
}

// ---------------- small per-graph kernels ----------------
// segment softmax stats; also zeros pooled for the gemm_feat that follows
__global__ __launch_bounds__(256) void k_gseg(const float* __restrict__ gate,
                                              const int* __restrict__ gstart,
                                              float* __restrict__ gmax,
                                              float* __restrict__ denom,
                                              float* __restrict__ pooled) {
    int g = blockIdx.x;
    int t = threadIdx.x;
    if (t < EMB) pooled[(size_t)g * EMB + t] = 0.f;
    int s0 = gstart[g], s1 = gstart[g + 1];
    __shared__ float red[256];
    float mx = -__builtin_inff();
    for (int i = s0 + t; i < s1; i += 256) mx = fmaxf(mx, gate[i]);
    red[t] = mx;
    __syncthreads();
#pragma unroll
    for (int off = 128; off; off >>= 1) {
        if (t < off) red[t] = fmaxf(red[t], red[t + off]);
        __syncthreads();
    }
    float m = red[0];
    __syncthreads();
    float sum = 0.f;
    for (int i = s0 + t; i < s1; i += 256) sum += __expf(gate[i] - m);
    red[t] = sum;
    __syncthreads();
#pragma unroll
    for (int off = 128; off; off >>= 1) {
        if (t < off) red[t] += red[t + off];
        __syncthreads();
    }
    if (t == 0) {
        gmax[g] = (s1 > s0) ? m : 0.f;
        denom[g] = red[0];
    }
}

// xg_out = lrelu([pooled, xg] @ Wt + bt) + xg ; fused: gb for NEXT step
// (last step: xg_out points directly into d_out -- no trailing memcpy)
__global__ __launch_bounds__(128) void k_xg(const float* __restrict__ pooled,
                                            const float* __restrict__ xg,
                                            const float* __restrict__ Wt,
                                            const float* __restrict__ bt,
                                            float* __restrict__ xg_out,
                                            const float* __restrict__ WaGn,
                                            const float* __restrict__ ban,
                                            float* __restrict__ gb) {
    int g = blockIdx.x, c = threadIdx.x;
    __shared__ float row[256];
    row[c] = pooled[(size_t)g * EMB + c];
    row[c + 128] = xg[(size_t)g * EMB + c];
    __syncthreads();
    float acc = bt[c];
#pragma unroll 8
    for (int k = 0; k < 256; ++k) acc = fmaf(row[k], Wt[(size_t)k * EMB + c], acc);
    float v = lrelu(acc) + row[c + 128];
    xg_out[(size_t)g * EMB + c] = v;
    if (WaGn) {
        __syncthreads();
        row[c] = v;
        __syncthreads();
        float a2 = ban[c];
#pragma unroll 8
        for (int k = 0; k < EMB; ++k) a2 = fmaf(row[k], WaGn[(size_t)k * EMB + c], a2);
        gb[(size_t)g * EMB + c] = a2;
    }
}

// ---------------- fused edge-message MFMA + segment-max ----------------
// 256-thread blocks; each wave owns FOUR adjacent nodes, phase-split:
// (A) all 4 nodes' srcp+ea loads, (B) all 16 h-gathers, (C) 32 MFMAs+max --
// 4 independent chains per wave (latency-bound kernel; extends the proven
// 2-node interleave). All array indices compile-time. deg>16 tails sequential.
__global__ __launch_bounds__(256) void k_fagg(const unsigned short* __restrict__ h,
                                              const unsigned short* __restrict__ ea16p,
                                              const int* __restrict__ srcp,
                                              const int* __restrict__ rowptr,
                                              const unsigned short* __restrict__ Bp,
                                              unsigned short* __restrict__ agg, int N) {
    __shared__ unsigned short lB[4096];   // Wm_e: [ctile(8)][lane(64)][j(8)] = 8KB
    int tid = threadIdx.x;
    ((int4*)lB)[tid]       = ((const int4*)Bp)[tid];
    ((int4*)lB)[tid + 256] = ((const int4*)Bp)[tid + 256];
    __syncthreads();
    int wv = tid >> 6, lane = tid & 63;
    int li = lane & 15, oct = lane >> 4;
    int n0 = blockIdx.x * 16 + wv * 4;
    if (n0 >= N) return;

    int r[5];
#pragma unroll
    for (int i = 0; i <= 4; ++i) {
        int idx = n0 + i; if (idx > N) idx = N;
        r[i] = rowptr[idx];
    }
    int deg[4];
#pragma unroll
    for (int i = 0; i < 4; ++i) deg[i] = r[i + 1] - r[i];

    float vm[4][8];
#pragma unroll
    for (int i = 0; i < 4; ++i)
#pragma unroll
        for (int ci = 0; ci < 8; ++ci) vm[i][ci] = -__builtin_inff();

    union HV { bf8s v; unsigned short s[8]; };
    // ---- phase A: slot loads for all 4 nodes ----
    int srcv[4]; bf8s a[4];
#pragma unroll
    for (int i = 0; i < 4; ++i) {
        int p = r[i] + li;
        int hi = r[i + 1] - 1;
        if (p > hi) p = (hi >= r[i]) ? hi : 0;   // deg==0 -> dummy slot 0
        srcv[i] = srcp[p];
        a[i] = *(const bf8s*)&ea16p[(size_t)p * EDGE + oct * 8];
    }
    // ---- phase B: h-gathers for all 4 nodes ----
    HV hv[4][4];
#pragma unroll
    for (int i = 0; i < 4; ++i) {
#pragma unroll
        for (int rr = 0; rr < 4; ++rr) {
            int sr = __shfl(srcv[i], oct * 4 + rr, 16);
            if (oct * 4 + rr >= deg[i]) sr = N;   // sentinel: h[N][*] = -inf
            hv[i][rr].v = *(const bf8s*)&h[(size_t)sr * EMB + li * 8];
        }
    }
    // ---- phase C: MFMAs + max ----
#pragma unroll
    for (int i = 0; i < 4; ++i) {
#pragma unroll
        for (int ci = 0; ci < 8; ++ci) {
            bf8s bb = *(const bf8s*)&lB[(ci * 64 + lane) * 8];
            f32x4 acc;
            acc[0] = bf2f(hv[i][0].s[ci]);
            acc[1] = bf2f(hv[i][1].s[ci]);
            acc[2] = bf2f(hv[i][2].s[ci]);
            acc[3] = bf2f(hv[i][3].s[ci]);
            acc = __builtin_amdgcn_mfma_f32_16x16x32_bf16(a[i], bb, acc, 0, 0, 0);
#pragma unroll
            for (int rr = 0; rr < 4; ++rr) vm[i][ci] = fmaxf(vm[i][ci], acc[rr]);
        }
    }
    // ---- rare tails (deg > 16), sequential per node ----
#pragma unroll
    for (int i = 0; i < 4; ++i) {
        for (int b = 16; b < deg[i]; b += 16) {
            int p = r[i] + b + li;
            if (p > r[i + 1] - 1) p = r[i + 1] - 1;
            int sv = srcp[p];
            bf8s at = *(const bf8s*)&ea16p[(size_t)p * EDGE + oct * 8];
            HV hvt[4];
#pragma unroll
            for (int rr = 0; rr < 4; ++rr) {
                int sr = __shfl(sv, oct * 4 + rr, 16);
                if (b + oct * 4 + rr >= deg[i]) sr = N;
                hvt[rr].v = *(const bf8s*)&h[(size_t)sr * EMB + li * 8];
            }
#pragma unroll
            for (int ci = 0; ci < 8; ++ci) {
                bf8s bb = *(const bf8s*)&lB[(ci * 64 + lane) * 8];
                f32x4 acc;
                acc[0] = bf2f(hvt[0].s[ci]);
                acc[1] = bf2f(hvt[1].s[ci]);
                acc[2] = bf2f(hvt[2].s[ci]);
                acc[3] = bf2f(hvt[3].s[ci]);
                acc = __builtin_amdgcn_mfma_f32_16x16x32_bf16(at, bb, acc, 0, 0, 0);
#pragma unroll
                for (int rr = 0; rr < 4; ++rr) vm[i][ci] = fmaxf(vm[i][ci], acc[rr]);
            }
        }
    }
    // ---- epilogues ----
#pragma unroll
    for (int i = 0; i < 4; ++i) {
        if (n0 + i >= N) break;   // wave-uniform
#pragma unroll
        for (int ci = 0; ci < 8; ++ci) {
            vm[i][ci] = fmaxf(vm[i][ci], __shfl_xor(vm[i][ci], 16, 64));
            vm[i][ci] = fmaxf(vm[i][ci], __shfl_xor(vm[i][ci], 32, 64));
        }
        float s0 = (oct == 0) ? vm[i][0] : (oct == 1) ? vm[i][1] : (oct == 2) ? vm[i][2] : vm[i][3];
        float s1 = (oct == 0) ? vm[i][4] : (oct == 1) ? vm[i][5] : (oct == 2) ? vm[i][6] : vm[i][7];
        s0 = lrelu(s0);
        s1 = lrelu(s1);
        if (deg[i] == 0) { s0 = 0.f; s1 = 0.f; }
        agg[(size_t)(n0 + i) * EMB + oct * 16 + li]       = f2bf(s0);
        agg[(size_t)(n0 + i) * EMB + (oct + 4) * 16 + li] = f2bf(s1);
    }
}

// ---------------- launch ----------------
extern "C" void kernel_launch(void* const* d_in, const int* in_sizes, int n_in,
                              void* d_out, int out_size, void* d_ws, size_t ws_size,
                              hipStream_t stream) {
    const float* x0    = (const float*)d_in[0];
    const float* ea    = (const float*)d_in[1];
    const float* Wm    = (const float*)d_in[2];
    const float* bm    = (const float*)d_in[3];
    const float* Wa    = (const float*)d_in[4];
    const float* ba    = (const float*)d_in[5];
    const float* Wgate = (const float*)d_in[6];
    const float* bgate = (const float*)d_in[7];
    const float* Wfeat = (const float*)d_in[8];
    const float* bfeat = (const float*)d_in[9];
    const float* Wt    = (const float*)d_in[10];
    const float* bt    = (const float*)d_in[11];
    const int*   eidx  = (const int*)d_in[12];
    const int*   batch = (const int*)d_in[13];

    int N = in_sizes[0] / EMB;
    int E = in_sizes[1] / EDGE;
    int G = in_sizes[15];

    char* w = (char*)d_ws;
    auto alloc = [&](size_t bytes) {
        char* p = w;
        w += (bytes + 255) & ~(size_t)255;
        return p;
    };
    unsigned short* h16   = (unsigned short*)alloc((size_t)(N + 1) * EMB * 2); // +1 sentinel
    unsigned short* x16   = (unsigned short*)alloc((size_t)N * EMB * 2);
    unsigned short* agg16 = (unsigned short*)alloc((size_t)N * EMB * 2);
    float* gate   = (float*)alloc((size_t)N * 4);
    float* gb     = (float*)alloc((size_t)G * EMB * 4);
    float* pooled = (float*)alloc((size_t)G * EMB * 4);
    float* gmax   = (float*)alloc((size_t)G * 4);
    float* denom  = (float*)alloc((size_t)G * 4);
    float* xg_a   = (float*)alloc((size_t)G * EMB * 4);
    float* xg_b   = (float*)alloc((size_t)G * EMB * 4);
    int* deg      = (int*)alloc((size_t)N * 4);
    int* rowptr   = (int*)alloc((size_t)(N + 1) * 4);
    int* cursor   = (int*)alloc((size_t)N * 4);
    int2* sp2     = (int2*)alloc((size_t)E * 8);
    int* srcp     = (int*)alloc((size_t)E * 4);
    unsigned short* ea16p = (unsigned short*)alloc((size_t)E * EDGE * 2);
    int* gstart   = (int*)alloc((size_t)(G + 1) * 4);
    int* bsums    = (int*)alloc(1024 * 4);
    unsigned short* wpack = (unsigned short*)alloc((size_t)15 * 16384 * 2);

    const int* esrc = eidx;
    const int* edst = eidx + E;
    int ebl = (E + 255) / 256;
    int NB  = (N + 255) / 256;
    int XB  = ((size_t)N * EMB / 8 + 255) / 256;

    k_setup<<<XB + NB + G + 1, 256, 0, stream>>>(x0, x16, N, XB, NB, ba, gb, xg_a,
                                                 batch, gstart, G, h16, deg);
    k_hist<<<ebl, 256, 0, stream>>>(edst, E, deg);
    k_scan1<<<NB, 256, 0, stream>>>(deg, N, rowptr, bsums);
    k_scan2<<<1, 256, 0, stream>>>(bsums, NB);
    k_scan3<<<NB, 256, 0, stream>>>(rowptr, bsums, cursor, N, E);
    k_fill<<<ebl, 256, 0, stream>>>(esrc, edst, E, cursor, sp2);
    k_eaperm<<<ebl, 256, 0, stream>>>(ea, sp2, ea16p, srcp, E);
    k_wpack<<<960, 256, 0, stream>>>(Wm, Wa, Wfeat, wpack);

    int gemm_blocks = (N + 127) / 128;
    int fagg_blocks = (N + 15) / 16;

    float* xg_cur = xg_a;
    float* xg_nxt = xg_b;

    for (int s = 0; s < STEPS; ++s) {
        const unsigned short* wp = wpack + (size_t)s * 5 * 16384;
        bool last = (s == STEPS - 1);

        k_gemm_bias<<<gemm_blocks, 256, 0, stream>>>(x16, wp + 0 * 16384, bm + s * EMB,
                                                     h16, N);
        k_fagg<<<fagg_blocks, 256, 0, stream>>>(h16, ea16p, srcp, rowptr, wp + 1 * 16384,
                                                agg16, N);
        k_gemm_node<<<gemm_blocks, 256, 0, stream>>>(x16, agg16, wp + 2 * 16384,
                                                     wp + 3 * 16384, gb, batch,
                                                     last ? (float*)d_out : nullptr,
                                                     Wgate + s * EMB, bgate + s, gate, N);
        k_gseg<<<G, 256, 0, stream>>>(gate, gstart, gmax, denom, pooled);
        k_gemm_feat<<<gemm_blocks, 256, 0, stream>>>(x16, wp + 4 * 16384, bfeat + s * EMB,
                                                     gate, gmax, denom, batch, pooled, N);
        const float* WaGn = !last ? Wa + (size_t)(s + 1) * 384 * EMB + 128 * EMB : nullptr;
        const float* ban  = !last ? ba + (s + 1) * EMB : nullptr;
        float* xgout = last ? (float*)d_out + (size_t)N * EMB : xg_nxt;
        k_xg<<<G, 128, 0, stream>>>(pooled, xg_cur, Wt + (size_t)s * 256 * EMB,
                                    bt + s * EMB, xgout, WaGn, ban, gb);

        float* tmp = xg_cur; xg_cur = xg_nxt; xg_nxt = tmp;
    }
}

// Round 10
// 548.207 us; speedup vs baseline: 1.5072x; 1.5072x over previous
//
#include <hip/hip_runtime.h>
#include <hip/hip_bf16.h>

#define EMB 128
#define EDGE 32
#define STEPS 3

typedef short bf8s __attribute__((ext_vector_type(8)));
typedef float f32x4 __attribute__((ext_vector_type(4)));

__device__ __forceinline__ float lrelu(float v) { return v > 0.0f ? v : 0.01f * v; }
__device__ __forceinline__ unsigned short f2bf(float f) {
    unsigned u = __float_as_uint(f);
    u += 0x7fffu + ((u >> 16) & 1u);
    return (unsigned short)(u >> 16);
}
__device__ __forceinline__ float bf2f(unsigned short s) {
    return __uint_as_float(((unsigned)s) << 16);
}
// packed fp32x2 -> bf16x2 (v_cvt_pk_bf16_f32 on gfx950)
__device__ __forceinline__ unsigned pk2bf(float x, float y) {
    __hip_bfloat162 h = __float22bfloat162_rn(make_float2(x, y));
    return *(unsigned*)&h;
}

// ---------------- CSR build ----------------
__global__ void k_hist(const int* __restrict__ dst, int E, int* __restrict__ deg) {
    int e = blockIdx.x * 256 + threadIdx.x;
    if (e < E) atomicAdd(&deg[dst[e]], 1);
}

__global__ void k_scan1(const int* __restrict__ deg, int N, int* __restrict__ rowptr,
                        int* __restrict__ bsums) {
    __shared__ int s[256];
    int t = threadIdx.x;
    int i = blockIdx.x * 256 + t;
    int v = (i < N) ? deg[i] : 0;
    s[t] = v;
    __syncthreads();
#pragma unroll
    for (int off = 1; off < 256; off <<= 1) {
        int x = (t >= off) ? s[t - off] : 0;
        __syncthreads();
        s[t] += x;
        __syncthreads();
    }
    if (i < N) rowptr[i] = s[t] - v;
    if (t == 255) bsums[blockIdx.x] = s[255];
}

__global__ void k_scan2(int* __restrict__ bsums, int NB) {
    __shared__ int s[256];
    __shared__ int carry;
    int t = threadIdx.x;
    if (t == 0) carry = 0;
    __syncthreads();
    for (int base = 0; base < NB; base += 256) {
        int i = base + t;
        int v = (i < NB) ? bsums[i] : 0;
        s[t] = v;
        __syncthreads();
#pragma unroll
        for (int off = 1; off < 256; off <<= 1) {
            int x = (t >= off) ? s[t - off] : 0;
            __syncthreads();
            s[t] += x;
            __syncthreads();
        }
        int excl = s[t] - v + carry;
        if (i < NB) bsums[i] = excl;
        int tot = s[255];
        __syncthreads();
        if (t == 0) carry += tot;
        __syncthreads();
    }
}

// also materializes cursor (= rowptr copy) so no D2D memcpy is needed
__global__ void k_scan3(int* __restrict__ rowptr, const int* __restrict__ bsums,
                        int* __restrict__ cursor, int N, int E) {
    int i = blockIdx.x * 256 + threadIdx.x;
    if (i < N) {
        int v = rowptr[i] + bsums[i >> 8];
        rowptr[i] = v;
        cursor[i] = v;
    }
    if (i == 0) rowptr[N] = E;
}

// fill: CSR permutation -- scatter ONLY an 8B (src,e) record per edge.
__global__ void k_fill(const int* __restrict__ src, const int* __restrict__ dst, int E,
                       int* __restrict__ cursor, int2* __restrict__ sp2) {
    int e = blockIdx.x * 256 + threadIdx.x;
    if (e >= E) return;
    int d = dst[e];
    int p = atomicAdd(&cursor[d], 1);
    sp2[p] = make_int2(src[e], e);
}

// eaperm: p-contiguous pass. Reads sp2[p] (contiguous), gathers ea[e] as one
// FULL 128B line (no read amplification), writes bf16 row ea16p[p] and srcp[p]
// contiguously (perfectly coalesced).
__global__ __launch_bounds__(256) void k_eaperm(const float* __restrict__ ea,
                                                const int2* __restrict__ sp2,
                                                unsigned short* __restrict__ ea16p,
                                                int* __restrict__ srcp, int E) {
    int p = blockIdx.x * 256 + threadIdx.x;
    if (p >= E) return;
    int2 sp = sp2[p];
    srcp[p] = sp.x;
    const float4* er = (const float4*)(ea + (size_t)sp.y * EDGE);
    union { unsigned u[16]; int4 v[4]; } o;
#pragma unroll
    for (int q = 0; q < 8; ++q) {
        float4 v = er[q];
        o.u[2 * q]     = pk2bf(v.x, v.y);
        o.u[2 * q + 1] = pk2bf(v.z, v.w);
    }
    int4* dp = (int4*)(ea16p + (size_t)p * EDGE);
#pragma unroll
    for (int q = 0; q < 4; ++q) dp[q] = o.v[q];
}

// ---------------- fused one-time setup ----------------
// block ranges: [0,XB) x0->x16 bf16 cvt | [XB,XB+NB) zero deg |
// [XB+NB, XB+NB+G) gb0 + zero xg_a + gstart[g] | last block: hsent + gstart[G]
__global__ __launch_bounds__(256) void k_setup(const float* __restrict__ x0,
                                               unsigned short* __restrict__ x16,
                                               int N, int XB, int NB,
                                               const float* __restrict__ ba,
                                               float* __restrict__ gb,
                                               float* __restrict__ xg_a,
                                               const int* __restrict__ batch,
                                               int* __restrict__ gstart, int G,
                                               unsigned short* __restrict__ h16,
                                               int* __restrict__ deg) {
    int b = blockIdx.x, t = threadIdx.x;
    if (b < XB) {
        size_t idx = ((size_t)b * 256 + t) * 8;
        if (idx < (size_t)N * EMB) {
            const float4* s = (const float4*)(x0 + idx);
            float4 v0 = s[0], v1 = s[1];
            union { bf8s v; unsigned u[4]; } o;
            o.u[0] = pk2bf(v0.x, v0.y);
            o.u[1] = pk2bf(v0.z, v0.w);
            o.u[2] = pk2bf(v1.x, v1.y);
            o.u[3] = pk2bf(v1.z, v1.w);
            *(bf8s*)(x16 + idx) = o.v;
        }
        return;
    }
    b -= XB;
    if (b < NB) {
        int i = b * 256 + t;
        if (i < N) deg[i] = 0;
        return;
    }
    b -= NB;
    if (b < G) {
        if (t < EMB) gb[(size_t)b * EMB + t] = ba[t];
        else xg_a[(size_t)b * EMB + (t - EMB)] = 0.f;
        if (t == 0) {
            int lo = 0, hi = N;
            while (lo < hi) {
                int mid = (lo + hi) >> 1;
                if (batch[mid] < b) lo = mid + 1; else hi = mid;
            }
            gstart[b] = lo;
        }
        return;
    }
    // last block
    if (t < EMB) h16[(size_t)N * EMB + t] = 0xFF80u;   // -inf sentinel row
    if (t == EMB) gstart[G] = N;
}

// ---------------- weight prepack: fp32 row-major -> bf16 B-fragment order ----------------
__global__ __launch_bounds__(256) void k_wpack(const float* __restrict__ Wm,
                                               const float* __restrict__ Wa,
                                               const float* __restrict__ Wfeat,
                                               unsigned short* __restrict__ wpack) {
    int gid = blockIdx.x * 256 + threadIdx.x;
    int unit = gid >> 14;
    int e = gid & 16383;
    int s = unit / 5, u = unit % 5;
    const float* src; int rows;
    switch (u) {
        case 0: src = Wm + (size_t)s * 160 * EMB;             rows = 128; break;
        case 1: src = Wm + (size_t)s * 160 * EMB + 128 * EMB; rows = 32;  break;
        case 2: src = Wa + (size_t)s * 384 * EMB;             rows = 128; break;
        case 3: src = Wa + (size_t)s * 384 * EMB + 256 * EMB; rows = 128; break;
        default: src = Wfeat + (size_t)s * EMB * EMB;         rows = 128; break;
    }
    int k = e >> 7, n = e & 127;
    if (k >= rows) return;
    unsigned short b = f2bf(src[(size_t)k * EMB + n]);
    int kc = k >> 5, c = n >> 4, lane = (n & 15) | (((k & 31) >> 3) << 4), j = k & 7;
    wpack[(size_t)unit * 16384 + ((size_t)(kc * 8 + c) * 64 + lane) * 8 + j] = b;
}

// ---------------- MFMA GEMM core: 64 rows x 128 cols, K=128 ----------------
// bf16 row-major A source: lane (li,oct) owns row row0+wv*16+li, k-chunk kc.
__device__ __forceinline__ void loadAa(const unsigned short* __restrict__ A16, int row0,
                                       int wv, int lane, int N, bf8s af[4]) {
    int li = lane & 15, oct = lane >> 4;
    int m = row0 + wv * 16 + li;
    if (m >= N) m = N - 1;
    const bf8s* ar = (const bf8s*)(A16 + (size_t)m * EMB);
#pragma unroll
    for (int kc = 0; kc < 4; ++kc) af[kc] = ar[kc * 4 + oct];
}
__device__ __forceinline__ void stageB(const unsigned short* __restrict__ Bp,
                                       unsigned short* lB, int tid) {
#pragma unroll
    for (int i = 0; i < 8; ++i) {
        int idx = tid + i * 256;
        ((int4*)lB)[idx] = ((const int4*)Bp)[idx];
    }
}
__device__ __forceinline__ void mfma128r(const bf8s af[4], const unsigned short* lB,
                                         f32x4 acc[8], int lane) {
#pragma unroll
    for (int kc = 0; kc < 4; ++kc) {
#pragma unroll
        for (int c = 0; c < 8; ++c) {
            bf8s b = *(const bf8s*)&lB[((kc * 8 + c) * 64 + lane) * 8];
            acc[c] = __builtin_amdgcn_mfma_f32_16x16x32_bf16(af[kc], b, acc[c], 0, 0, 0);
        }
    }
}

// h16 = bf16(x @ Wm_x + bm), stored COLUMN-SWIZZLED: natural col c lives at
// position (c&15)*8 + (c>>4). This makes the k_fagg h-gather for lane li
// (cols {ci*16+li : ci=0..7}) ONE contiguous 16B load at offset li*8.
__global__ __launch_bounds__(256) void k_gemm_bias(const unsigned short* __restrict__ A16,
                                                   const unsigned short* __restrict__ Bp,
                                                   const float* __restrict__ bias,
                                                   unsigned short* __restrict__ C, int N) {
    __shared__ unsigned short lB[16384];
    int tid = threadIdx.x, wv = tid >> 6, lane = tid & 63;
    int row0 = blockIdx.x * 64;
    stageB(Bp, lB, tid);
    bf8s af[4];
    loadAa(A16, row0, wv, lane, N, af);
    __syncthreads();
    f32x4 acc[8];
#pragma unroll
    for (int c = 0; c < 8; ++c) acc[c] = (f32x4){0.f, 0.f, 0.f, 0.f};
    mfma128r(af, lB, acc, lane);
    int li = lane & 15, quad = lane >> 4;
    float bcol[8];
#pragma unroll
    for (int c = 0; c < 8; ++c) bcol[c] = bias[c * 16 + li];
#pragma unroll
    for (int rr = 0; rr < 4; ++rr) {
        int m = row0 + wv * 16 + quad * 4 + rr;
        if (m < N) {
            union { bf8s v; unsigned u[4]; } o;
#pragma unroll
            for (int j = 0; j < 4; ++j)
                o.u[j] = pk2bf(acc[2 * j][rr] + bcol[2 * j],
                               acc[2 * j + 1][rr] + bcol[2 * j + 1]);
            *(bf8s*)&C[(size_t)m * EMB + li * 8] = o.v;
        }
    }
}

// x_new = lrelu(x@Wa_x + agg16@Wa_agg + gb[batch]) + x ; fused gate = x_new.wg+bg
// NODE STATE IS bf16 (x16): residual read from x16, updated x written to x16.
// The fp32 value is materialized ONLY on the last step, straight into d_out.
__global__ __launch_bounds__(256) void k_gemm_node(unsigned short* __restrict__ x16,
                                                   const unsigned short* __restrict__ agg16,
                                                   const unsigned short* __restrict__ BpX,
                                                   const unsigned short* __restrict__ BpA,
                                                   const float* __restrict__ gb,
                                                   const int* __restrict__ batch,
                                                   float* __restrict__ xout_f32, // d_out or null
                                                   const float* __restrict__ wg,
                                                   const float* __restrict__ bg,
                                                   float* __restrict__ gate, int N) {
    __shared__ unsigned short lB[16384];
    int tid = threadIdx.x, wv = tid >> 6, lane = tid & 63;
    int row0 = blockIdx.x * 64;
    stageB(BpX, lB, tid);
    bf8s af[4];
    loadAa(x16, row0, wv, lane, N, af);
    __syncthreads();
    f32x4 acc[8];
#pragma unroll
    for (int c = 0; c < 8; ++c) acc[c] = (f32x4){0.f, 0.f, 0.f, 0.f};
    mfma128r(af, lB, acc, lane);
    __syncthreads();
    stageB(BpA, lB, tid);
    loadAa(agg16, row0, wv, lane, N, af);
    __syncthreads();
    mfma128r(af, lB, acc, lane);
    int li = lane & 15, quad = lane >> 4;
    float gpart[4] = {0.f, 0.f, 0.f, 0.f};
#pragma unroll
    for (int c = 0; c < 8; ++c) {
        int col = c * 16 + li;
        float wgc = wg[col];
#pragma unroll
        for (int rr = 0; rr < 4; ++rr) {
            int m = row0 + wv * 16 + quad * 4 + rr;
            if (m < N) {
                int g = batch[m];
                float b = gb[(size_t)g * EMB + col];
                float res = bf2f(x16[(size_t)m * EMB + col]);
                float v = lrelu(acc[c][rr] + b) + res;
                x16[(size_t)m * EMB + col] = f2bf(v);
                if (xout_f32) xout_f32[(size_t)m * EMB + col] = v;
                gpart[rr] = fmaf(v, wgc, gpart[rr]);
            }
        }
    }
#pragma unroll
    for (int rr = 0; rr < 4; ++rr) {
#pragma unroll
        for (int off = 1; off < 16; off <<= 1)
            gpart[rr] += __shfl_xor(gpart[rr], off, 64);
    }
    if (li == 0) {
        float b0 = bg[0];
#pragma unroll
        for (int rr = 0; rr < 4; ++rr) {
            int m = row0 + wv * 16 + quad * 4 + rr;
            if (m < N) gate[m] = gpart[rr] + b0;
        }
    }
}

// pooled += alpha * lrelu(x@Wfeat + bfeat), accumulated directly (no ft16).
__global__ __launch_bounds__(256) void k_gemm_feat(const unsigned short* __restrict__ A16,
                                                   const unsigned short* __restrict__ Bp,
                                                   const float* __restrict__ bias,
                                                   const float* __restrict__ gate,
                                                   const float* __restrict__ gmax,
                                                   const float* __restrict__ denom,
                                                   const int* __restrict__ batch,
                                                   float* __restrict__ pooled, int N) {
    __shared__ unsigned short lB[16384];
    int tid = threadIdx.x, wv = tid >> 6, lane = tid & 63;
    int row0 = blockIdx.x * 64;
    stageB(Bp, lB, tid);
    bf8s af[4];
    loadAa(A16, row0, wv, lane, N, af);
    __syncthreads();
    f32x4 acc[8];
#pragma unroll
    for (int c = 0; c < 8; ++c) acc[c] = (f32x4){0.f, 0.f, 0.f, 0.f};
    mfma128r(af, lB, acc, lane);
    int li = lane & 15, quad = lane >> 4;
    int rb = row0 + wv * 16;
    if (rb >= N) return;
    float alpha[4];
    int grow[4];
#pragma unroll
    for (int rr = 0; rr < 4; ++rr) {
        int m = rb + quad * 4 + rr;
        if (m < N) {
            int g = batch[m];
            grow[rr] = g;
            alpha[rr] = __expf(gate[m] - gmax[g]) / denom[g];
        } else { alpha[rr] = 0.f; grow[rr] = 0; }
    }
    int gs = batch[rb];
    int mlast = rb + 15; if (mlast >= N) mlast = N - 1;
    bool uni = (gs == batch[mlast]);
#pragma unroll
    for (int c = 0; c < 8; ++c) {
        int col = c * 16 + li;
        float b = bias[col];
        float v0 = alpha[0] * lrelu(acc[c][0] + b);
        float v1 = alpha[1] * lrelu(acc[c][1] + b);
        float v2 = alpha[2] * lrelu(acc[c][2] + b);
        float v3 = alpha[3] * lrelu(acc[c][3] + b);
        if (uni) {
            float s = (v0 + v1) + (v2 + v3);
            s += __shfl_xor(s, 16, 64);
            s += __shfl_xor(s, 32, 64);
            if (quad == 0) atomicAdd(&pooled[(size_t)gs * EMB + col], s);
        } else {
            if (rb + quad * 4 + 0 < N) atomicAdd(&pooled[(size_t)grow[0] * EMB + col], v0);
            if (rb + quad * 4 + 1 < N) atomicAdd(&pooled[(size_t)grow[1] * EMB + col], v1);
            if (rb + quad * 4 + 2 < N) atomicAdd(&pooled[(size_t)grow[2] * EMB + col], v2);
            if (rb + quad * 4 + 3 < N) atomicAdd(&pooled[(size_t)grow[3] * EMB + col], v3);
        }
    }
}

// ---------------- small per-graph kernels ----------------
// segment softmax stats; also zeros pooled for the gemm_feat that follows
__global__ __launch_bounds__(256) void k_gseg(const float* __restrict__ gate,
                                              const int* __restrict__ gstart,
                                              float* __restrict__ gmax,
                                              float* __restrict__ denom,
                                              float* __restrict__ pooled) {
    int g = blockIdx.x;
    int t = threadIdx.x;
    if (t < EMB) pooled[(size_t)g * EMB + t] = 0.f;
    int s0 = gstart[g], s1 = gstart[g + 1];
    __shared__ float red[256];
    float mx = -__builtin_inff();
    for (int i = s0 + t; i < s1; i += 256) mx = fmaxf(mx, gate[i]);
    red[t] = mx;
    __syncthreads();
#pragma unroll
    for (int off = 128; off; off >>= 1) {
        if (t < off) red[t] = fmaxf(red[t], red[t + off]);
        __syncthreads();
    }
    float m = red[0];
    __syncthreads();
    float sum = 0.f;
    for (int i = s0 + t; i < s1; i += 256) sum += __expf(gate[i] - m);
    red[t] = sum;
    __syncthreads();
#pragma unroll
    for (int off = 128; off; off >>= 1) {
        if (t < off) red[t] += red[t + off];
        __syncthreads();
    }
    if (t == 0) {
        gmax[g] = (s1 > s0) ? m : 0.f;
        denom[g] = red[0];
    }
}

// xg_out = lrelu([pooled, xg] @ Wt + bt) + xg ; fused: gb for NEXT step
// (last step: xg_out points directly into d_out -- no trailing memcpy)
__global__ __launch_bounds__(128) void k_xg(const float* __restrict__ pooled,
                                            const float* __restrict__ xg,
                                            const float* __restrict__ Wt,
                                            const float* __restrict__ bt,
                                            float* __restrict__ xg_out,
                                            const float* __restrict__ WaGn,
                                            const float* __restrict__ ban,
                                            float* __restrict__ gb) {
    int g = blockIdx.x, c = threadIdx.x;
    __shared__ float row[256];
    row[c] = pooled[(size_t)g * EMB + c];
    row[c + 128] = xg[(size_t)g * EMB + c];
    __syncthreads();
    float acc = bt[c];
#pragma unroll 8
    for (int k = 0; k < 256; ++k) acc = fmaf(row[k], Wt[(size_t)k * EMB + c], acc);
    float v = lrelu(acc) + row[c + 128];
    xg_out[(size_t)g * EMB + c] = v;
    if (WaGn) {
        __syncthreads();
        row[c] = v;
        __syncthreads();
        float a2 = ban[c];
#pragma unroll 8
        for (int k = 0; k < EMB; ++k) a2 = fmaf(row[k], WaGn[(size_t)k * EMB + c], a2);
        gb[(size_t)g * EMB + c] = a2;
    }
}

// ---------------- fused edge-message MFMA + segment-max ----------------
// PERSISTENT grid-stride version of the R7-proven 2-node-per-wave kernel:
// fixed 2048-block grid (8 blocks/CU at launch); each wave loops over node
// pairs with stride gridDim*8. Amortizes the 8KB Wm_e staging ~3x and keeps
// waves resident (R7 measured only ~9 waves/CU on 12.5k short blocks).
// Per-pair body identical to R7 (proven): interleaved A/B load chains.
__global__ __launch_bounds__(256) void k_fagg(const unsigned short* __restrict__ h,
                                              const unsigned short* __restrict__ ea16p,
                                              const int* __restrict__ srcp,
                                              const int* __restrict__ rowptr,
                                              const unsigned short* __restrict__ Bp,
                                              unsigned short* __restrict__ agg, int N) {
    __shared__ unsigned short lB[4096];   // Wm_e: [ctile(8)][lane(64)][j(8)] = 8KB
    int tid = threadIdx.x;
    ((int4*)lB)[tid]       = ((const int4*)Bp)[tid];
    ((int4*)lB)[tid + 256] = ((const int4*)Bp)[tid + 256];
    __syncthreads();
    int wv = tid >> 6, lane = tid & 63;
    int li = lane & 15, oct = lane >> 4;
    int stride = gridDim.x * 8;

    for (int nA = blockIdx.x * 8 + wv * 2; nA < N; nA += stride) {
        int nB = nA + 1;
        bool hasB = (nB < N);
        int r0 = rowptr[nA];
        int r1 = rowptr[nA + 1];
        int r2 = hasB ? rowptr[nB + 1] : r1;
        int degA = r1 - r0, degB = r2 - r1;

        float vmA[8], vmB[8];
#pragma unroll
        for (int ci = 0; ci < 8; ++ci) { vmA[ci] = -__builtin_inff(); vmB[ci] = -__builtin_inff(); }

        // ---- first batch of BOTH nodes, loads interleaved for MLP ----
        {
            int pA = r0 + li; if (pA >= r1) pA = (r1 > r0) ? r1 - 1 : 0;
            int pB = r1 + li; if (pB >= r2) pB = (r2 > r1) ? r2 - 1 : 0;
            int srcvA = srcp[pA];
            int srcvB = srcp[pB];
            bf8s aA = *(const bf8s*)&ea16p[(size_t)pA * EDGE + oct * 8];
            bf8s aB = *(const bf8s*)&ea16p[(size_t)pB * EDGE + oct * 8];
            union { bf8s v; unsigned short s[8]; } hvA[4], hvB[4];
#pragma unroll
            for (int rr = 0; rr < 4; ++rr) {
                int sr = __shfl(srcvA, oct * 4 + rr, 16);
                if (oct * 4 + rr >= degA) sr = N;
                hvA[rr].v = *(const bf8s*)&h[(size_t)sr * EMB + li * 8];
            }
#pragma unroll
            for (int rr = 0; rr < 4; ++rr) {
                int sr = __shfl(srcvB, oct * 4 + rr, 16);
                if (oct * 4 + rr >= degB) sr = N;
                hvB[rr].v = *(const bf8s*)&h[(size_t)sr * EMB + li * 8];
            }
#pragma unroll
            for (int ci = 0; ci < 8; ++ci) {
                bf8s bb = *(const bf8s*)&lB[(ci * 64 + lane) * 8];
                f32x4 acc;
                acc[0] = bf2f(hvA[0].s[ci]);
                acc[1] = bf2f(hvA[1].s[ci]);
                acc[2] = bf2f(hvA[2].s[ci]);
                acc[3] = bf2f(hvA[3].s[ci]);
                acc = __builtin_amdgcn_mfma_f32_16x16x32_bf16(aA, bb, acc, 0, 0, 0);
#pragma unroll
                for (int rr = 0; rr < 4; ++rr) vmA[ci] = fmaxf(vmA[ci], acc[rr]);
            }
#pragma unroll
            for (int ci = 0; ci < 8; ++ci) {
                bf8s bb = *(const bf8s*)&lB[(ci * 64 + lane) * 8];
                f32x4 acc;
                acc[0] = bf2f(hvB[0].s[ci]);
                acc[1] = bf2f(hvB[1].s[ci]);
                acc[2] = bf2f(hvB[2].s[ci]);
                acc[3] = bf2f(hvB[3].s[ci]);
                acc = __builtin_amdgcn_mfma_f32_16x16x32_bf16(aB, bb, acc, 0, 0, 0);
#pragma unroll
                for (int rr = 0; rr < 4; ++rr) vmB[ci] = fmaxf(vmB[ci], acc[rr]);
            }
        }
        // ---- rare tails (deg > 16) ----
        for (int b = 16; b < degA; b += 16) {
            int p = r0 + b + li;
            if (p > r1 - 1) p = r1 - 1;
            int srcv = srcp[p];
            bf8s a = *(const bf8s*)&ea16p[(size_t)p * EDGE + oct * 8];
            union { bf8s v; unsigned short s[8]; } hv[4];
#pragma unroll
            for (int rr = 0; rr < 4; ++rr) {
                int sr = __shfl(srcv, oct * 4 + rr, 16);
                if (b + oct * 4 + rr >= degA) sr = N;
                hv[rr].v = *(const bf8s*)&h[(size_t)sr * EMB + li * 8];
            }
#pragma unroll
            for (int ci = 0; ci < 8; ++ci) {
                bf8s bb = *(const bf8s*)&lB[(ci * 64 + lane) * 8];
                f32x4 acc;
                acc[0] = bf2f(hv[0].s[ci]);
                acc[1] = bf2f(hv[1].s[ci]);
                acc[2] = bf2f(hv[2].s[ci]);
                acc[3] = bf2f(hv[3].s[ci]);
                acc = __builtin_amdgcn_mfma_f32_16x16x32_bf16(a, bb, acc, 0, 0, 0);
#pragma unroll
                for (int rr = 0; rr < 4; ++rr) vmA[ci] = fmaxf(vmA[ci], acc[rr]);
            }
        }
        for (int b = 16; b < degB; b += 16) {
            int p = r1 + b + li;
            if (p > r2 - 1) p = r2 - 1;
            int srcv = srcp[p];
            bf8s a = *(const bf8s*)&ea16p[(size_t)p * EDGE + oct * 8];
            union { bf8s v; unsigned short s[8]; } hv[4];
#pragma unroll
            for (int rr = 0; rr < 4; ++rr) {
                int sr = __shfl(srcv, oct * 4 + rr, 16);
                if (b + oct * 4 + rr >= degB) sr = N;
                hv[rr].v = *(const bf8s*)&h[(size_t)sr * EMB + li * 8];
            }
#pragma unroll
            for (int ci = 0; ci < 8; ++ci) {
                bf8s bb = *(const bf8s*)&lB[(ci * 64 + lane) * 8];
                f32x4 acc;
                acc[0] = bf2f(hv[0].s[ci]);
                acc[1] = bf2f(hv[1].s[ci]);
                acc[2] = bf2f(hv[2].s[ci]);
                acc[3] = bf2f(hv[3].s[ci]);
                acc = __builtin_amdgcn_mfma_f32_16x16x32_bf16(a, bb, acc, 0, 0, 0);
#pragma unroll
                for (int rr = 0; rr < 4; ++rr) vmB[ci] = fmaxf(vmB[ci], acc[rr]);
            }
        }
        // ---- epilogues ----
#pragma unroll
        for (int ci = 0; ci < 8; ++ci) {
            vmA[ci] = fmaxf(vmA[ci], __shfl_xor(vmA[ci], 16, 64));
            vmA[ci] = fmaxf(vmA[ci], __shfl_xor(vmA[ci], 32, 64));
            vmB[ci] = fmaxf(vmB[ci], __shfl_xor(vmB[ci], 16, 64));
            vmB[ci] = fmaxf(vmB[ci], __shfl_xor(vmB[ci], 32, 64));
        }
        {
            float s0 = (oct == 0) ? vmA[0] : (oct == 1) ? vmA[1] : (oct == 2) ? vmA[2] : vmA[3];
            float s1 = (oct == 0) ? vmA[4] : (oct == 1) ? vmA[5] : (oct == 2) ? vmA[6] : vmA[7];
            s0 = lrelu(s0);
            s1 = lrelu(s1);
            if (degA == 0) { s0 = 0.f; s1 = 0.f; }
            agg[(size_t)nA * EMB + oct * 16 + li]       = f2bf(s0);
            agg[(size_t)nA * EMB + (oct + 4) * 16 + li] = f2bf(s1);
        }
        if (hasB) {
            float s0 = (oct == 0) ? vmB[0] : (oct == 1) ? vmB[1] : (oct == 2) ? vmB[2] : vmB[3];
            float s1 = (oct == 0) ? vmB[4] : (oct == 1) ? vmB[5] : (oct == 2) ? vmB[6] : vmB[7];
            s0 = lrelu(s0);
            s1 = lrelu(s1);
            if (degB == 0) { s0 = 0.f; s1 = 0.f; }
            agg[(size_t)nB * EMB + oct * 16 + li]       = f2bf(s0);
            agg[(size_t)nB * EMB + (oct + 4) * 16 + li] = f2bf(s1);
        }
    }
}

// ---------------- launch ----------------
extern "C" void kernel_launch(void* const* d_in, const int* in_sizes, int n_in,
                              void* d_out, int out_size, void* d_ws, size_t ws_size,
                              hipStream_t stream) {
    const float* x0    = (const float*)d_in[0];
    const float* ea    = (const float*)d_in[1];
    const float* Wm    = (const float*)d_in[2];
    const float* bm    = (const float*)d_in[3];
    const float* Wa    = (const float*)d_in[4];
    const float* ba    = (const float*)d_in[5];
    const float* Wgate = (const float*)d_in[6];
    const float* bgate = (const float*)d_in[7];
    const float* Wfeat = (const float*)d_in[8];
    const float* bfeat = (const float*)d_in[9];
    const float* Wt    = (const float*)d_in[10];
    const float* bt    = (const float*)d_in[11];
    const int*   eidx  = (const int*)d_in[12];
    const int*   batch = (const int*)d_in[13];

    int N = in_sizes[0] / EMB;
    int E = in_sizes[1] / EDGE;
    int G = in_sizes[15];

    char* w = (char*)d_ws;
    auto alloc = [&](size_t bytes) {
        char* p = w;
        w += (bytes + 255) & ~(size_t)255;
        return p;
    };
    unsigned short* h16   = (unsigned short*)alloc((size_t)(N + 1) * EMB * 2); // +1 sentinel
    unsigned short* x16   = (unsigned short*)alloc((size_t)N * EMB * 2);
    unsigned short* agg16 = (unsigned short*)alloc((size_t)N * EMB * 2);
    float* gate   = (float*)alloc((size_t)N * 4);
    float* gb     = (float*)alloc((size_t)G * EMB * 4);
    float* pooled = (float*)alloc((size_t)G * EMB * 4);
    float* gmax   = (float*)alloc((size_t)G * 4);
    float* denom  = (float*)alloc((size_t)G * 4);
    float* xg_a   = (float*)alloc((size_t)G * EMB * 4);
    float* xg_b   = (float*)alloc((size_t)G * EMB * 4);
    int* deg      = (int*)alloc((size_t)N * 4);
    int* rowptr   = (int*)alloc((size_t)(N + 1) * 4);
    int* cursor   = (int*)alloc((size_t)N * 4);
    int2* sp2     = (int2*)alloc((size_t)E * 8);
    int* srcp     = (int*)alloc((size_t)E * 4);
    unsigned short* ea16p = (unsigned short*)alloc((size_t)E * EDGE * 2);
    int* gstart   = (int*)alloc((size_t)(G + 1) * 4);
    int* bsums    = (int*)alloc(1024 * 4);
    unsigned short* wpack = (unsigned short*)alloc((size_t)15 * 16384 * 2);

    const int* esrc = eidx;
    const int* edst = eidx + E;
    int ebl = (E + 255) / 256;
    int NB  = (N + 255) / 256;
    int XB  = ((size_t)N * EMB / 8 + 255) / 256;

    k_setup<<<XB + NB + G + 1, 256, 0, stream>>>(x0, x16, N, XB, NB, ba, gb, xg_a,
                                                 batch, gstart, G, h16, deg);
    k_hist<<<ebl, 256, 0, stream>>>(edst, E, deg);
    k_scan1<<<NB, 256, 0, stream>>>(deg, N, rowptr, bsums);
    k_scan2<<<1, 256, 0, stream>>>(bsums, NB);
    k_scan3<<<NB, 256, 0, stream>>>(rowptr, bsums, cursor, N, E);
    k_fill<<<ebl, 256, 0, stream>>>(esrc, edst, E, cursor, sp2);
    k_eaperm<<<ebl, 256, 0, stream>>>(ea, sp2, ea16p, srcp, E);
    k_wpack<<<960, 256, 0, stream>>>(Wm, Wa, Wfeat, wpack);

    int gemm_blocks = (N + 63) / 64;
    int fagg_blocks = 2048;
    if (fagg_blocks > (N + 7) / 8) fagg_blocks = (N + 7) / 8;

    float* xg_cur = xg_a;
    float* xg_nxt = xg_b;

    for (int s = 0; s < STEPS; ++s) {
        const unsigned short* wp = wpack + (size_t)s * 5 * 16384;
        bool last = (s == STEPS - 1);

        k_gemm_bias<<<gemm_blocks, 256, 0, stream>>>(x16, wp + 0 * 16384, bm + s * EMB,
                                                     h16, N);
        k_fagg<<<fagg_blocks, 256, 0, stream>>>(h16, ea16p, srcp, rowptr, wp + 1 * 16384,
                                                agg16, N);
        k_gemm_node<<<gemm_blocks, 256, 0, stream>>>(x16, agg16, wp + 2 * 16384,
                                                     wp + 3 * 16384, gb, batch,
                                                     last ? (float*)d_out : nullptr,
                                                     Wgate + s * EMB, bgate + s, gate, N);
        k_gseg<<<G, 256, 0, stream>>>(gate, gstart, gmax, denom, pooled);
        k_gemm_feat<<<gemm_blocks, 256, 0, stream>>>(x16, wp + 4 * 16384, bfeat + s * EMB,
                                                     gate, gmax, denom, batch, pooled, N);
        const float* WaGn = !last ? Wa + (size_t)(s + 1) * 384 * EMB + 128 * EMB : nullptr;
        const float* ban  = !last ? ba + (s + 1) * EMB : nullptr;
        float* xgout = last ? (float*)d_out + (size_t)N * EMB : xg_nxt;
        k_xg<<<G, 128, 0, stream>>>(pooled, xg_cur, Wt + (size_t)s * 256 * EMB,
                                    bt + s * EMB, xgout, WaGn, ban, gb);

        float* tmp = xg_cur; xg_cur = xg_nxt; xg_nxt = tmp;
    }
}

// Round 11
// 518.405 us; speedup vs baseline: 1.5938x; 1.0575x over previous
//
#include <hip/hip_runtime.h>
#include <hip/hip_bf16.h>

#define EMB 128
#define EDGE 32
#define STEPS 3

typedef short bf8s __attribute__((ext_vector_type(8)));
typedef float f32x4 __attribute__((ext_vector_type(4)));

__device__ __forceinline__ float lrelu(float v) { return v > 0.0f ? v : 0.01f * v; }
__device__ __forceinline__ unsigned short f2bf(float f) {
    unsigned u = __float_as_uint(f);
    u += 0x7fffu + ((u >> 16) & 1u);
    return (unsigned short)(u >> 16);
}
__device__ __forceinline__ float bf2f(unsigned short s) {
    return __uint_as_float(((unsigned)s) << 16);
}
// packed fp32x2 -> bf16x2 (v_cvt_pk_bf16_f32 on gfx950)
__device__ __forceinline__ unsigned pk2bf(float x, float y) {
    __hip_bfloat162 h = __float22bfloat162_rn(make_float2(x, y));
    return *(unsigned*)&h;
}

// ---------------- CSR build ----------------
__global__ void k_hist(const int* __restrict__ dst, int E, int* __restrict__ deg) {
    int e = blockIdx.x * 256 + threadIdx.x;
    if (e < E) atomicAdd(&deg[dst[e]], 1);
}

__global__ void k_scan1(const int* __restrict__ deg, int N, int* __restrict__ rowptr,
                        int* __restrict__ bsums) {
    __shared__ int s[256];
    int t = threadIdx.x;
    int i = blockIdx.x * 256 + t;
    int v = (i < N) ? deg[i] : 0;
    s[t] = v;
    __syncthreads();
#pragma unroll
    for (int off = 1; off < 256; off <<= 1) {
        int x = (t >= off) ? s[t - off] : 0;
        __syncthreads();
        s[t] += x;
        __syncthreads();
    }
    if (i < N) rowptr[i] = s[t] - v;
    if (t == 255) bsums[blockIdx.x] = s[255];
}

__global__ void k_scan2(int* __restrict__ bsums, int NB) {
    __shared__ int s[256];
    __shared__ int carry;
    int t = threadIdx.x;
    if (t == 0) carry = 0;
    __syncthreads();
    for (int base = 0; base < NB; base += 256) {
        int i = base + t;
        int v = (i < NB) ? bsums[i] : 0;
        s[t] = v;
        __syncthreads();
#pragma unroll
        for (int off = 1; off < 256; off <<= 1) {
            int x = (t >= off) ? s[t - off] : 0;
            __syncthreads();
            s[t] += x;
            __syncthreads();
        }
        int excl = s[t] - v + carry;
        if (i < NB) bsums[i] = excl;
        int tot = s[255];
        __syncthreads();
        if (t == 0) carry += tot;
        __syncthreads();
    }
}

// also materializes cursor (= rowptr copy) so no D2D memcpy is needed
__global__ void k_scan3(int* __restrict__ rowptr, const int* __restrict__ bsums,
                        int* __restrict__ cursor, int N, int E) {
    int i = blockIdx.x * 256 + threadIdx.x;
    if (i < N) {
        int v = rowptr[i] + bsums[i >> 8];
        rowptr[i] = v;
        cursor[i] = v;
    }
    if (i == 0) rowptr[N] = E;
}

// fill: CSR permutation -- scatter ONLY an 8B (src,e) record per edge.
__global__ void k_fill(const int* __restrict__ src, const int* __restrict__ dst, int E,
                       int* __restrict__ cursor, int2* __restrict__ sp2) {
    int e = blockIdx.x * 256 + threadIdx.x;
    if (e >= E) return;
    int d = dst[e];
    int p = atomicAdd(&cursor[d], 1);
    sp2[p] = make_int2(src[e], e);
}

// eaperm: p-contiguous pass. Reads sp2[p] (contiguous), gathers ea[e] as one
// FULL 128B line (no read amplification), writes bf16 row ea16p[p] and srcp[p]
// contiguously (perfectly coalesced).
__global__ __launch_bounds__(256) void k_eaperm(const float* __restrict__ ea,
                                                const int2* __restrict__ sp2,
                                                unsigned short* __restrict__ ea16p,
                                                int* __restrict__ srcp, int E) {
    int p = blockIdx.x * 256 + threadIdx.x;
    if (p >= E) return;
    int2 sp = sp2[p];
    srcp[p] = sp.x;
    const float4* er = (const float4*)(ea + (size_t)sp.y * EDGE);
    union { unsigned u[16]; int4 v[4]; } o;
#pragma unroll
    for (int q = 0; q < 8; ++q) {
        float4 v = er[q];
        o.u[2 * q]     = pk2bf(v.x, v.y);
        o.u[2 * q + 1] = pk2bf(v.z, v.w);
    }
    int4* dp = (int4*)(ea16p + (size_t)p * EDGE);
#pragma unroll
    for (int q = 0; q < 4; ++q) dp[q] = o.v[q];
}

// ---------------- fused one-time setup ----------------
// block ranges: [0,XB) x0->x16 bf16 cvt | [XB,XB+NB) zero deg |
// [XB+NB, XB+NB+G) gb0 + zero xg_a + gstart[g] | last block: hsent + gstart[G]
__global__ __launch_bounds__(256) void k_setup(const float* __restrict__ x0,
                                               unsigned short* __restrict__ x16,
                                               int N, int XB, int NB,
                                               const float* __restrict__ ba,
                                               float* __restrict__ gb,
                                               float* __restrict__ xg_a,
                                               const int* __restrict__ batch,
                                               int* __restrict__ gstart, int G,
                                               unsigned short* __restrict__ h16,
                                               int* __restrict__ deg) {
    int b = blockIdx.x, t = threadIdx.x;
    if (b < XB) {
        size_t idx = ((size_t)b * 256 + t) * 8;
        if (idx < (size_t)N * EMB) {
            const float4* s = (const float4*)(x0 + idx);
            float4 v0 = s[0], v1 = s[1];
            union { bf8s v; unsigned u[4]; } o;
            o.u[0] = pk2bf(v0.x, v0.y);
            o.u[1] = pk2bf(v0.z, v0.w);
            o.u[2] = pk2bf(v1.x, v1.y);
            o.u[3] = pk2bf(v1.z, v1.w);
            *(bf8s*)(x16 + idx) = o.v;
        }
        return;
    }
    b -= XB;
    if (b < NB) {
        int i = b * 256 + t;
        if (i < N) deg[i] = 0;
        return;
    }
    b -= NB;
    if (b < G) {
        if (t < EMB) gb[(size_t)b * EMB + t] = ba[t];
        else xg_a[(size_t)b * EMB + (t - EMB)] = 0.f;
        if (t == 0) {
            int lo = 0, hi = N;
            while (lo < hi) {
                int mid = (lo + hi) >> 1;
                if (batch[mid] < b) lo = mid + 1; else hi = mid;
            }
            gstart[b] = lo;
        }
        return;
    }
    // last block
    if (t < EMB) h16[(size_t)N * EMB + t] = 0xFF80u;   // -inf sentinel row
    if (t == EMB) gstart[G] = N;
}

// ---------------- weight prepack: fp32 row-major -> bf16 B-fragment order ----------------
__global__ __launch_bounds__(256) void k_wpack(const float* __restrict__ Wm,
                                               const float* __restrict__ Wa,
                                               const float* __restrict__ Wfeat,
                                               unsigned short* __restrict__ wpack) {
    int gid = blockIdx.x * 256 + threadIdx.x;
    int unit = gid >> 14;
    int e = gid & 16383;
    int s = unit / 5, u = unit % 5;
    const float* src; int rows;
    switch (u) {
        case 0: src = Wm + (size_t)s * 160 * EMB;             rows = 128; break;
        case 1: src = Wm + (size_t)s * 160 * EMB + 128 * EMB; rows = 32;  break;
        case 2: src = Wa + (size_t)s * 384 * EMB;             rows = 128; break;
        case 3: src = Wa + (size_t)s * 384 * EMB + 256 * EMB; rows = 128; break;
        default: src = Wfeat + (size_t)s * EMB * EMB;         rows = 128; break;
    }
    int k = e >> 7, n = e & 127;
    if (k >= rows) return;
    unsigned short b = f2bf(src[(size_t)k * EMB + n]);
    int kc = k >> 5, c = n >> 4, lane = (n & 15) | (((k & 31) >> 3) << 4), j = k & 7;
    wpack[(size_t)unit * 16384 + ((size_t)(kc * 8 + c) * 64 + lane) * 8 + j] = b;
}

// ---------------- MFMA GEMM core: 64 rows x 128 cols, K=128 ----------------
// bf16 row-major A source: lane (li,oct) owns row row0+wv*16+li, k-chunk kc.
__device__ __forceinline__ void loadAa(const unsigned short* __restrict__ A16, int row0,
                                       int wv, int lane, int N, bf8s af[4]) {
    int li = lane & 15, oct = lane >> 4;
    int m = row0 + wv * 16 + li;
    if (m >= N) m = N - 1;
    const bf8s* ar = (const bf8s*)(A16 + (size_t)m * EMB);
#pragma unroll
    for (int kc = 0; kc < 4; ++kc) af[kc] = ar[kc * 4 + oct];
}
__device__ __forceinline__ void stageB(const unsigned short* __restrict__ Bp,
                                       unsigned short* lB, int tid) {
#pragma unroll
    for (int i = 0; i < 8; ++i) {
        int idx = tid + i * 256;
        ((int4*)lB)[idx] = ((const int4*)Bp)[idx];
    }
}
__device__ __forceinline__ void mfma128r(const bf8s af[4], const unsigned short* lB,
                                         f32x4 acc[8], int lane) {
#pragma unroll
    for (int kc = 0; kc < 4; ++kc) {
#pragma unroll
        for (int c = 0; c < 8; ++c) {
            bf8s b = *(const bf8s*)&lB[((kc * 8 + c) * 64 + lane) * 8];
            acc[c] = __builtin_amdgcn_mfma_f32_16x16x32_bf16(af[kc], b, acc[c], 0, 0, 0);
        }
    }
}

// h16 = bf16(x @ Wm_x + bm), stored COLUMN-SWIZZLED: natural col c lives at
// position (c&15)*8 + (c>>4). This makes the k_fagg h-gather for lane li
// (cols {ci*16+li : ci=0..7}) ONE contiguous 16B load at offset li*8.
__device__ __forceinline__ void bias_epi(const f32x4 acc[8], int row0, int wv, int lane,
                                         const float* __restrict__ bias,
                                         unsigned short* __restrict__ C, int N) {
    int li = lane & 15, quad = lane >> 4;
    float bcol[8];
#pragma unroll
    for (int c = 0; c < 8; ++c) bcol[c] = bias[c * 16 + li];
#pragma unroll
    for (int rr = 0; rr < 4; ++rr) {
        int m = row0 + wv * 16 + quad * 4 + rr;
        if (m < N) {
            union { bf8s v; unsigned u[4]; } o;
#pragma unroll
            for (int j = 0; j < 4; ++j)
                o.u[j] = pk2bf(acc[2 * j][rr] + bcol[2 * j],
                               acc[2 * j + 1][rr] + bcol[2 * j + 1]);
            *(bf8s*)&C[(size_t)m * EMB + li * 8] = o.v;
        }
    }
}

__global__ __launch_bounds__(256) void k_gemm_bias(const unsigned short* __restrict__ A16,
                                                   const unsigned short* __restrict__ Bp,
                                                   const float* __restrict__ bias,
                                                   unsigned short* __restrict__ C, int N) {
    __shared__ unsigned short lB[16384];
    int tid = threadIdx.x, wv = tid >> 6, lane = tid & 63;
    int row0 = blockIdx.x * 64;
    stageB(Bp, lB, tid);
    bf8s af[4];
    loadAa(A16, row0, wv, lane, N, af);
    __syncthreads();
    f32x4 acc[8];
#pragma unroll
    for (int c = 0; c < 8; ++c) acc[c] = (f32x4){0.f, 0.f, 0.f, 0.f};
    mfma128r(af, lB, acc, lane);
    bias_epi(acc, row0, wv, lane, bias, C, N);
}

// x_new = lrelu(x@Wa_x + agg16@Wa_agg + gb[batch]) + x ; fused gate = x_new.wg+bg
// NODE STATE IS bf16 (x16): residual read from x16, updated x written to x16.
// The fp32 value is materialized ONLY on the last step, straight into d_out.
__global__ __launch_bounds__(256) void k_gemm_node(unsigned short* __restrict__ x16,
                                                   const unsigned short* __restrict__ agg16,
                                                   const unsigned short* __restrict__ BpX,
                                                   const unsigned short* __restrict__ BpA,
                                                   const float* __restrict__ gb,
                                                   const int* __restrict__ batch,
                                                   float* __restrict__ xout_f32, // d_out or null
                                                   const float* __restrict__ wg,
                                                   const float* __restrict__ bg,
                                                   float* __restrict__ gate, int N) {
    __shared__ unsigned short lB[16384];
    int tid = threadIdx.x, wv = tid >> 6, lane = tid & 63;
    int row0 = blockIdx.x * 64;
    stageB(BpX, lB, tid);
    bf8s af[4];
    loadAa(x16, row0, wv, lane, N, af);
    __syncthreads();
    f32x4 acc[8];
#pragma unroll
    for (int c = 0; c < 8; ++c) acc[c] = (f32x4){0.f, 0.f, 0.f, 0.f};
    mfma128r(af, lB, acc, lane);
    __syncthreads();
    stageB(BpA, lB, tid);
    loadAa(agg16, row0, wv, lane, N, af);
    __syncthreads();
    mfma128r(af, lB, acc, lane);
    int li = lane & 15, quad = lane >> 4;
    float gpart[4] = {0.f, 0.f, 0.f, 0.f};
#pragma unroll
    for (int c = 0; c < 8; ++c) {
        int col = c * 16 + li;
        float wgc = wg[col];
#pragma unroll
        for (int rr = 0; rr < 4; ++rr) {
            int m = row0 + wv * 16 + quad * 4 + rr;
            if (m < N) {
                int g = batch[m];
                float b = gb[(size_t)g * EMB + col];
                float res = bf2f(x16[(size_t)m * EMB + col]);
                float v = lrelu(acc[c][rr] + b) + res;
                x16[(size_t)m * EMB + col] = f2bf(v);
                if (xout_f32) xout_f32[(size_t)m * EMB + col] = v;
                gpart[rr] = fmaf(v, wgc, gpart[rr]);
            }
        }
    }
#pragma unroll
    for (int rr = 0; rr < 4; ++rr) {
#pragma unroll
        for (int off = 1; off < 16; off <<= 1)
            gpart[rr] += __shfl_xor(gpart[rr], off, 64);
    }
    if (li == 0) {
        float b0 = bg[0];
#pragma unroll
        for (int rr = 0; rr < 4; ++rr) {
            int m = row0 + wv * 16 + quad * 4 + rr;
            if (m < N) gate[m] = gpart[rr] + b0;
        }
    }
}

// feat epilogue: pooled += alpha * lrelu(acc + bfeat) via per-wave reduced atomics.
__device__ __forceinline__ void feat_epi(const f32x4 acc[8], int row0, int wv, int lane,
                                         const float* __restrict__ bias,
                                         const float* __restrict__ gate,
                                         const float* __restrict__ gmax,
                                         const float* __restrict__ denom,
                                         const int* __restrict__ batch,
                                         float* __restrict__ pooled, int N) {
    int li = lane & 15, quad = lane >> 4;
    int rb = row0 + wv * 16;
    if (rb >= N) return;
    float alpha[4];
    int grow[4];
#pragma unroll
    for (int rr = 0; rr < 4; ++rr) {
        int m = rb + quad * 4 + rr;
        if (m < N) {
            int g = batch[m];
            grow[rr] = g;
            alpha[rr] = __expf(gate[m] - gmax[g]) / denom[g];
        } else { alpha[rr] = 0.f; grow[rr] = 0; }
    }
    int gs = batch[rb];
    int mlast = rb + 15; if (mlast >= N) mlast = N - 1;
    bool uni = (gs == batch[mlast]);
#pragma unroll
    for (int c = 0; c < 8; ++c) {
        int col = c * 16 + li;
        float b = bias[col];
        float v0 = alpha[0] * lrelu(acc[c][0] + b);
        float v1 = alpha[1] * lrelu(acc[c][1] + b);
        float v2 = alpha[2] * lrelu(acc[c][2] + b);
        float v3 = alpha[3] * lrelu(acc[c][3] + b);
        if (uni) {
            float s = (v0 + v1) + (v2 + v3);
            s += __shfl_xor(s, 16, 64);
            s += __shfl_xor(s, 32, 64);
            if (quad == 0) atomicAdd(&pooled[(size_t)gs * EMB + col], s);
        } else {
            if (rb + quad * 4 + 0 < N) atomicAdd(&pooled[(size_t)grow[0] * EMB + col], v0);
            if (rb + quad * 4 + 1 < N) atomicAdd(&pooled[(size_t)grow[1] * EMB + col], v1);
            if (rb + quad * 4 + 2 < N) atomicAdd(&pooled[(size_t)grow[2] * EMB + col], v2);
            if (rb + quad * 4 + 3 < N) atomicAdd(&pooled[(size_t)grow[3] * EMB + col], v3);
        }
    }
}

// standalone feat (last step only)
__global__ __launch_bounds__(256) void k_gemm_feat(const unsigned short* __restrict__ A16,
                                                   const unsigned short* __restrict__ Bp,
                                                   const float* __restrict__ bias,
                                                   const float* __restrict__ gate,
                                                   const float* __restrict__ gmax,
                                                   const float* __restrict__ denom,
                                                   const int* __restrict__ batch,
                                                   float* __restrict__ pooled, int N) {
    __shared__ unsigned short lB[16384];
    int tid = threadIdx.x, wv = tid >> 6, lane = tid & 63;
    int row0 = blockIdx.x * 64;
    stageB(Bp, lB, tid);
    bf8s af[4];
    loadAa(A16, row0, wv, lane, N, af);
    __syncthreads();
    f32x4 acc[8];
#pragma unroll
    for (int c = 0; c < 8; ++c) acc[c] = (f32x4){0.f, 0.f, 0.f, 0.f};
    mfma128r(af, lB, acc, lane);
    feat_epi(acc, row0, wv, lane, bias, gate, gmax, denom, batch, pooled, N);
}

// FUSED: feat(step s) + bias(step s+1). Both read the SAME x16 state (final
// after gemm_node(s)), so load A-fragments ONCE and run two GEMMs with
// two-phase 32KB staging (proven pattern from k_gemm_node). Saves a full
// 12.8MB x16 pass + one launch per fused step; numerics bit-identical.
__global__ __launch_bounds__(256) void k_gemm_fb(const unsigned short* __restrict__ A16,
                                                 const unsigned short* __restrict__ BpF,
                                                 const float* __restrict__ bfeat_s,
                                                 const float* __restrict__ gate,
                                                 const float* __restrict__ gmax,
                                                 const float* __restrict__ denom,
                                                 const int* __restrict__ batch,
                                                 float* __restrict__ pooled,
                                                 const unsigned short* __restrict__ BpBn,
                                                 const float* __restrict__ bm_next,
                                                 unsigned short* __restrict__ h16, int N) {
    __shared__ unsigned short lB[16384];
    int tid = threadIdx.x, wv = tid >> 6, lane = tid & 63;
    int row0 = blockIdx.x * 64;
    stageB(BpF, lB, tid);
    bf8s af[4];
    loadAa(A16, row0, wv, lane, N, af);
    __syncthreads();
    f32x4 accF[8], accB[8];
#pragma unroll
    for (int c = 0; c < 8; ++c) {
        accF[c] = (f32x4){0.f, 0.f, 0.f, 0.f};
        accB[c] = (f32x4){0.f, 0.f, 0.f, 0.f};
    }
    mfma128r(af, lB, accF, lane);
    __syncthreads();
    stageB(BpBn, lB, tid);
    __syncthreads();
    mfma128r(af, lB, accB, lane);
    feat_epi(accF, row0, wv, lane, bfeat_s, gate, gmax, denom, batch, pooled, N);
    bias_epi(accB, row0, wv, lane, bm_next, h16, N);
}

// ---------------- small per-graph kernels ----------------
// segment softmax stats; also zeros pooled for the gemm_feat that follows
__global__ __launch_bounds__(256) void k_gseg(const float* __restrict__ gate,
                                              const int* __restrict__ gstart,
                                              float* __restrict__ gmax,
                                              float* __restrict__ denom,
                                              float* __restrict__ pooled) {
    int g = blockIdx.x;
    int t = threadIdx.x;
    if (t < EMB) pooled[(size_t)g * EMB + t] = 0.f;
    int s0 = gstart[g], s1 = gstart[g + 1];
    __shared__ float red[256];
    float mx = -__builtin_inff();
    for (int i = s0 + t; i < s1; i += 256) mx = fmaxf(mx, gate[i]);
    red[t] = mx;
    __syncthreads();
#pragma unroll
    for (int off = 128; off; off >>= 1) {
        if (t < off) red[t] = fmaxf(red[t], red[t + off]);
        __syncthreads();
    }
    float m = red[0];
    __syncthreads();
    float sum = 0.f;
    for (int i = s0 + t; i < s1; i += 256) sum += __expf(gate[i] - m);
    red[t] = sum;
    __syncthreads();
#pragma unroll
    for (int off = 128; off; off >>= 1) {
        if (t < off) red[t] += red[t + off];
        __syncthreads();
    }
    if (t == 0) {
        gmax[g] = (s1 > s0) ? m : 0.f;
        denom[g] = red[0];
    }
}

// xg_out = lrelu([pooled, xg] @ Wt + bt) + xg ; fused: gb for NEXT step
// (last step: xg_out points directly into d_out -- no trailing memcpy)
__global__ __launch_bounds__(128) void k_xg(const float* __restrict__ pooled,
                                            const float* __restrict__ xg,
                                            const float* __restrict__ Wt,
                                            const float* __restrict__ bt,
                                            float* __restrict__ xg_out,
                                            const float* __restrict__ WaGn,
                                            const float* __restrict__ ban,
                                            float* __restrict__ gb) {
    int g = blockIdx.x, c = threadIdx.x;
    __shared__ float row[256];
    row[c] = pooled[(size_t)g * EMB + c];
    row[c + 128] = xg[(size_t)g * EMB + c];
    __syncthreads();
    float acc = bt[c];
#pragma unroll 8
    for (int k = 0; k < 256; ++k) acc = fmaf(row[k], Wt[(size_t)k * EMB + c], acc);
    float v = lrelu(acc) + row[c + 128];
    xg_out[(size_t)g * EMB + c] = v;
    if (WaGn) {
        __syncthreads();
        row[c] = v;
        __syncthreads();
        float a2 = ban[c];
#pragma unroll 8
        for (int k = 0; k < EMB; ++k) a2 = fmaf(row[k], WaGn[(size_t)k * EMB + c], a2);
        gb[(size_t)g * EMB + c] = a2;
    }
}

// ---------------- fused edge-message MFMA + segment-max ----------------
// R7-proven version: 256-thread blocks (4 waves); each wave owns TWO adjacent
// nodes with hand-interleaved first batches (latency-chain-bound kernel: MLP
// across the two independent chains). deg>16 tails sequential. Persistent
// (R10) and 4-node (R9) variants both failed to beat this.
__global__ __launch_bounds__(256) void k_fagg(const unsigned short* __restrict__ h,
                                              const unsigned short* __restrict__ ea16p,
                                              const int* __restrict__ srcp,
                                              const int* __restrict__ rowptr,
                                              const unsigned short* __restrict__ Bp,
                                              unsigned short* __restrict__ agg, int N) {
    __shared__ unsigned short lB[4096];   // Wm_e: [ctile(8)][lane(64)][j(8)]
    int tid = threadIdx.x;
    ((int4*)lB)[tid]       = ((const int4*)Bp)[tid];
    ((int4*)lB)[tid + 256] = ((const int4*)Bp)[tid + 256];
    __syncthreads();
    int wv = tid >> 6, lane = tid & 63;
    int li = lane & 15, oct = lane >> 4;
    int nA = blockIdx.x * 8 + wv * 2;
    if (nA >= N) return;
    int nB = nA + 1;
    bool hasB = (nB < N);
    int r0 = rowptr[nA];
    int r1 = rowptr[nA + 1];
    int r2 = hasB ? rowptr[nB + 1] : r1;
    int degA = r1 - r0, degB = r2 - r1;

    float vmA[8], vmB[8];
#pragma unroll
    for (int ci = 0; ci < 8; ++ci) { vmA[ci] = -__builtin_inff(); vmB[ci] = -__builtin_inff(); }

    // ---- first batch of BOTH nodes, loads interleaved for MLP ----
    {
        int pA = r0 + li; if (pA >= r1) pA = (r1 > r0) ? r1 - 1 : 0;
        int pB = r1 + li; if (pB >= r2) pB = (r2 > r1) ? r2 - 1 : 0;
        int srcvA = srcp[pA];
        int srcvB = srcp[pB];
        bf8s aA = *(const bf8s*)&ea16p[(size_t)pA * EDGE + oct * 8];
        bf8s aB = *(const bf8s*)&ea16p[(size_t)pB * EDGE + oct * 8];
        union { bf8s v; unsigned short s[8]; } hvA[4], hvB[4];
#pragma unroll
        for (int rr = 0; rr < 4; ++rr) {
            int sr = __shfl(srcvA, oct * 4 + rr, 16);
            if (oct * 4 + rr >= degA) sr = N;
            hvA[rr].v = *(const bf8s*)&h[(size_t)sr * EMB + li * 8];
        }
#pragma unroll
        for (int rr = 0; rr < 4; ++rr) {
            int sr = __shfl(srcvB, oct * 4 + rr, 16);
            if (oct * 4 + rr >= degB) sr = N;
            hvB[rr].v = *(const bf8s*)&h[(size_t)sr * EMB + li * 8];
        }
#pragma unroll
        for (int ci = 0; ci < 8; ++ci) {
            bf8s bb = *(const bf8s*)&lB[(ci * 64 + lane) * 8];
            f32x4 acc;
            acc[0] = bf2f(hvA[0].s[ci]);
            acc[1] = bf2f(hvA[1].s[ci]);
            acc[2] = bf2f(hvA[2].s[ci]);
            acc[3] = bf2f(hvA[3].s[ci]);
            acc = __builtin_amdgcn_mfma_f32_16x16x32_bf16(aA, bb, acc, 0, 0, 0);
#pragma unroll
            for (int rr = 0; rr < 4; ++rr) vmA[ci] = fmaxf(vmA[ci], acc[rr]);
        }
#pragma unroll
        for (int ci = 0; ci < 8; ++ci) {
            bf8s bb = *(const bf8s*)&lB[(ci * 64 + lane) * 8];
            f32x4 acc;
            acc[0] = bf2f(hvB[0].s[ci]);
            acc[1] = bf2f(hvB[1].s[ci]);
            acc[2] = bf2f(hvB[2].s[ci]);
            acc[3] = bf2f(hvB[3].s[ci]);
            acc = __builtin_amdgcn_mfma_f32_16x16x32_bf16(aB, bb, acc, 0, 0, 0);
#pragma unroll
            for (int rr = 0; rr < 4; ++rr) vmB[ci] = fmaxf(vmB[ci], acc[rr]);
        }
    }
    // ---- rare tails (deg > 16) ----
    for (int b = 16; b < degA; b += 16) {
        int p = r0 + b + li;
        if (p > r1 - 1) p = r1 - 1;
        int srcv = srcp[p];
        bf8s a = *(const bf8s*)&ea16p[(size_t)p * EDGE + oct * 8];
        union { bf8s v; unsigned short s[8]; } hv[4];
#pragma unroll
        for (int rr = 0; rr < 4; ++rr) {
            int sr = __shfl(srcv, oct * 4 + rr, 16);
            if (b + oct * 4 + rr >= degA) sr = N;
            hv[rr].v = *(const bf8s*)&h[(size_t)sr * EMB + li * 8];
        }
#pragma unroll
        for (int ci = 0; ci < 8; ++ci) {
            bf8s bb = *(const bf8s*)&lB[(ci * 64 + lane) * 8];
            f32x4 acc;
            acc[0] = bf2f(hv[0].s[ci]);
            acc[1] = bf2f(hv[1].s[ci]);
            acc[2] = bf2f(hv[2].s[ci]);
            acc[3] = bf2f(hv[3].s[ci]);
            acc = __builtin_amdgcn_mfma_f32_16x16x32_bf16(a, bb, acc, 0, 0, 0);
#pragma unroll
            for (int rr = 0; rr < 4; ++rr) vmA[ci] = fmaxf(vmA[ci], acc[rr]);
        }
    }
    for (int b = 16; b < degB; b += 16) {
        int p = r1 + b + li;
        if (p > r2 - 1) p = r2 - 1;
        int srcv = srcp[p];
        bf8s a = *(const bf8s*)&ea16p[(size_t)p * EDGE + oct * 8];
        union { bf8s v; unsigned short s[8]; } hv[4];
#pragma unroll
        for (int rr = 0; rr < 4; ++rr) {
            int sr = __shfl(srcv, oct * 4 + rr, 16);
            if (b + oct * 4 + rr >= degB) sr = N;
            hv[rr].v = *(const bf8s*)&h[(size_t)sr * EMB + li * 8];
        }
#pragma unroll
        for (int ci = 0; ci < 8; ++ci) {
            bf8s bb = *(const bf8s*)&lB[(ci * 64 + lane) * 8];
            f32x4 acc;
            acc[0] = bf2f(hv[0].s[ci]);
            acc[1] = bf2f(hv[1].s[ci]);
            acc[2] = bf2f(hv[2].s[ci]);
            acc[3] = bf2f(hv[3].s[ci]);
            acc = __builtin_amdgcn_mfma_f32_16x16x32_bf16(a, bb, acc, 0, 0, 0);
#pragma unroll
            for (int rr = 0; rr < 4; ++rr) vmB[ci] = fmaxf(vmB[ci], acc[rr]);
        }
    }
    // ---- epilogues ----
#pragma unroll
    for (int ci = 0; ci < 8; ++ci) {
        vmA[ci] = fmaxf(vmA[ci], __shfl_xor(vmA[ci], 16, 64));
        vmA[ci] = fmaxf(vmA[ci], __shfl_xor(vmA[ci], 32, 64));
        vmB[ci] = fmaxf(vmB[ci], __shfl_xor(vmB[ci], 16, 64));
        vmB[ci] = fmaxf(vmB[ci], __shfl_xor(vmB[ci], 32, 64));
    }
    {
        float s0 = (oct == 0) ? vmA[0] : (oct == 1) ? vmA[1] : (oct == 2) ? vmA[2] : vmA[3];
        float s1 = (oct == 0) ? vmA[4] : (oct == 1) ? vmA[5] : (oct == 2) ? vmA[6] : vmA[7];
        s0 = lrelu(s0);
        s1 = lrelu(s1);
        if (degA == 0) { s0 = 0.f; s1 = 0.f; }
        agg[(size_t)nA * EMB + oct * 16 + li]       = f2bf(s0);
        agg[(size_t)nA * EMB + (oct + 4) * 16 + li] = f2bf(s1);
    }
    if (hasB) {
        float s0 = (oct == 0) ? vmB[0] : (oct == 1) ? vmB[1] : (oct == 2) ? vmB[2] : vmB[3];
        float s1 = (oct == 0) ? vmB[4] : (oct == 1) ? vmB[5] : (oct == 2) ? vmB[6] : vmB[7];
        s0 = lrelu(s0);
        s1 = lrelu(s1);
        if (degB == 0) { s0 = 0.f; s1 = 0.f; }
        agg[(size_t)nB * EMB + oct * 16 + li]       = f2bf(s0);
        agg[(size_t)nB * EMB + (oct + 4) * 16 + li] = f2bf(s1);
    }
}

// ---------------- launch ----------------
extern "C" void kernel_launch(void* const* d_in, const int* in_sizes, int n_in,
                              void* d_out, int out_size, void* d_ws, size_t ws_size,
                              hipStream_t stream) {
    const float* x0    = (const float*)d_in[0];
    const float* ea    = (const float*)d_in[1];
    const float* Wm    = (const float*)d_in[2];
    const float* bm    = (const float*)d_in[3];
    const float* Wa    = (const float*)d_in[4];
    const float* ba    = (const float*)d_in[5];
    const float* Wgate = (const float*)d_in[6];
    const float* bgate = (const float*)d_in[7];
    const float* Wfeat = (const float*)d_in[8];
    const float* bfeat = (const float*)d_in[9];
    const float* Wt    = (const float*)d_in[10];
    const float* bt    = (const float*)d_in[11];
    const int*   eidx  = (const int*)d_in[12];
    const int*   batch = (const int*)d_in[13];

    int N = in_sizes[0] / EMB;
    int E = in_sizes[1] / EDGE;
    int G = in_sizes[15];

    char* w = (char*)d_ws;
    auto alloc = [&](size_t bytes) {
        char* p = w;
        w += (bytes + 255) & ~(size_t)255;
        return p;
    };
    unsigned short* h16   = (unsigned short*)alloc((size_t)(N + 1) * EMB * 2); // +1 sentinel
    unsigned short* x16   = (unsigned short*)alloc((size_t)N * EMB * 2);
    unsigned short* agg16 = (unsigned short*)alloc((size_t)N * EMB * 2);
    float* gate   = (float*)alloc((size_t)N * 4);
    float* gb     = (float*)alloc((size_t)G * EMB * 4);
    float* pooled = (float*)alloc((size_t)G * EMB * 4);
    float* gmax   = (float*)alloc((size_t)G * 4);
    float* denom  = (float*)alloc((size_t)G * 4);
    float* xg_a   = (float*)alloc((size_t)G * EMB * 4);
    float* xg_b   = (float*)alloc((size_t)G * EMB * 4);
    int* deg      = (int*)alloc((size_t)N * 4);
    int* rowptr   = (int*)alloc((size_t)(N + 1) * 4);
    int* cursor   = (int*)alloc((size_t)N * 4);
    int2* sp2     = (int2*)alloc((size_t)E * 8);
    int* srcp     = (int*)alloc((size_t)E * 4);
    unsigned short* ea16p = (unsigned short*)alloc((size_t)E * EDGE * 2);
    int* gstart   = (int*)alloc((size_t)(G + 1) * 4);
    int* bsums    = (int*)alloc(1024 * 4);
    unsigned short* wpack = (unsigned short*)alloc((size_t)15 * 16384 * 2);

    const int* esrc = eidx;
    const int* edst = eidx + E;
    int ebl = (E + 255) / 256;
    int NB  = (N + 255) / 256;
    int XB  = ((size_t)N * EMB / 8 + 255) / 256;

    k_setup<<<XB + NB + G + 1, 256, 0, stream>>>(x0, x16, N, XB, NB, ba, gb, xg_a,
                                                 batch, gstart, G, h16, deg);
    k_hist<<<ebl, 256, 0, stream>>>(edst, E, deg);
    k_scan1<<<NB, 256, 0, stream>>>(deg, N, rowptr, bsums);
    k_scan2<<<1, 256, 0, stream>>>(bsums, NB);
    k_scan3<<<NB, 256, 0, stream>>>(rowptr, bsums, cursor, N, E);
    k_fill<<<ebl, 256, 0, stream>>>(esrc, edst, E, cursor, sp2);
    k_eaperm<<<ebl, 256, 0, stream>>>(ea, sp2, ea16p, srcp, E);
    k_wpack<<<960, 256, 0, stream>>>(Wm, Wa, Wfeat, wpack);

    int gemm_blocks = (N + 63) / 64;
    int fagg_blocks = (N + 7) / 8;

    float* xg_cur = xg_a;
    float* xg_nxt = xg_b;

    // step-0 h16 (subsequent steps' h16 come fused from k_gemm_fb)
    k_gemm_bias<<<gemm_blocks, 256, 0, stream>>>(x16, wpack + 0 * 16384, bm, h16, N);

    for (int s = 0; s < STEPS; ++s) {
        const unsigned short* wp = wpack + (size_t)s * 5 * 16384;
        bool last = (s == STEPS - 1);

        k_fagg<<<fagg_blocks, 256, 0, stream>>>(h16, ea16p, srcp, rowptr, wp + 1 * 16384,
                                                agg16, N);
        k_gemm_node<<<gemm_blocks, 256, 0, stream>>>(x16, agg16, wp + 2 * 16384,
                                                     wp + 3 * 16384, gb, batch,
                                                     last ? (float*)d_out : nullptr,
                                                     Wgate + s * EMB, bgate + s, gate, N);
        k_gseg<<<G, 256, 0, stream>>>(gate, gstart, gmax, denom, pooled);
        if (!last) {
            // fused: feat(s) + bias(s+1) -- one x16 pass for both GEMMs
            k_gemm_fb<<<gemm_blocks, 256, 0, stream>>>(x16, wp + 4 * 16384, bfeat + s * EMB,
                                                       gate, gmax, denom, batch, pooled,
                                                       wp + 5 * 16384 /* next step unit0 */,
                                                       bm + (s + 1) * EMB, h16, N);
        } else {
            k_gemm_feat<<<gemm_blocks, 256, 0, stream>>>(x16, wp + 4 * 16384,
                                                         bfeat + s * EMB, gate, gmax,
                                                         denom, batch, pooled, N);
        }
        const float* WaGn = !last ? Wa + (size_t)(s + 1) * 384 * EMB + 128 * EMB : nullptr;
        const float* ban  = !last ? ba + (s + 1) * EMB : nullptr;
        float* xgout = last ? (float*)d_out + (size_t)N * EMB : xg_nxt;
        k_xg<<<G, 128, 0, stream>>>(pooled, xg_cur, Wt + (size_t)s * 256 * EMB,
                                    bt + s * EMB, xgout, WaGn, ban, gb);

        float* tmp = xg_cur; xg_cur = xg_nxt; xg_nxt = tmp;
    }
}